// Round 6
// baseline (193.423 us; speedup 1.0000x reference)
//
#include <hip/hip_runtime.h>
#include <stdint.h>

// Problem constants
#define SEQ   4096
#define DIMM  512
#define HDIM  64
#define NH    8
#define ROWS  8192          // B*N = 2*4096
#define QKVN  1536          // 3*DIM

typedef __attribute__((ext_vector_type(8))) __bf16 bf16x8;   // MFMA A/B frag (4 VGPRs)
typedef __attribute__((ext_vector_type(4))) float  f32x4;    // MFMA C/D frag
typedef __attribute__((ext_vector_type(4))) uint32_t u32x4;

// packed fp32x2 -> bf16x2 (RNE) in ONE VALU op. low16 = bf16(lo), hi16 = bf16(hi).
__device__ __forceinline__ uint32_t cvtpk(float lo, float hi) {
  uint32_t w;
  asm("v_cvt_pk_bf16_f32 %0, %1, %2" : "=v"(w) : "v"(lo), "v"(hi));
  return w;
}

// gfx950 cross-lane half-swaps (VALU pipe, NOT LDS).
__device__ __forceinline__ void swap32(uint32_t& a, uint32_t& b) {
  asm("v_permlane32_swap_b32 %0, %1" : "+v"(a), "+v"(b));
}
__device__ __forceinline__ void swap16(uint32_t& a, uint32_t& b) {
  asm("v_permlane16_swap_b32 %0, %1" : "+v"(a), "+v"(b));
}

__device__ __forceinline__ f32x4 mfma16(bf16x8 a, bf16x8 b, f32x4 c) {
  return __builtin_amdgcn_mfma_f32_16x16x32_bf16(a, b, c, 0, 0, 0);
}

#if __has_builtin(__builtin_amdgcn_exp2f)
#define EXP2F(x) __builtin_amdgcn_exp2f(x)
#else
#define EXP2F(x) exp2f(x)
#endif

// async global->LDS, 16B per lane. LDS dest is wave-uniform base + lane*16;
// the GLOBAL address is per-lane free -> we use it to store XOR-swizzled tiles.
__device__ __forceinline__ void gld16(const void* g, void* l) {
  __builtin_amdgcn_global_load_lds(
      (const __attribute__((address_space(1))) uint32_t*)g,
      (__attribute__((address_space(3))) uint32_t*)l, 16, 0, 0);
}

// ---------------------------------------------------------------------------
// Kernel 1: fp32 -> bf16 conversion of x, w_qkv, w_proj (one grid, 3 segments)
// ---------------------------------------------------------------------------
#define X4  (ROWS * DIMM / 4)    // 1048576
#define Q4  (QKVN * DIMM / 4)    // 196608
#define P4  (DIMM * DIMM / 4)    // 65536

__global__ __launch_bounds__(256) void cvt_kernel(
    const float* __restrict__ x, const float* __restrict__ wq,
    const float* __restrict__ wp, uint16_t* __restrict__ xb,
    uint16_t* __restrict__ wqb, uint16_t* __restrict__ wpb) {
  int idx = blockIdx.x * 256 + threadIdx.x;    // float4 index
  const float* src; uint16_t* dst; int i4;
  if (idx < X4)            { src = x;  dst = xb;  i4 = idx; }
  else if (idx < X4 + Q4)  { src = wq; dst = wqb; i4 = idx - X4; }
  else                     { src = wp; dst = wpb; i4 = idx - X4 - Q4; }
  float4 v = ((const float4*)src)[i4];
  uint2 o;
  o.x = cvtpk(v.x, v.y);
  o.y = cvtpk(v.z, v.w);
  ((uint2*)dst)[i4] = o;
}

// ---------------------------------------------------------------------------
// Shared GEMM core: C[128x128] = A[128xK] * B[128xK]^T  (both row-major, K=512)
// 256 threads = 4 waves in 2x2, each wave 64x64 via 4x4 MFMA frags.
// Double-buffered LDS [2][128][32] bf16; ONE __syncthreads per K-step.
// bm/bn passed in (XCD-swizzled by caller). swizzle c' = c ^ ((r>>1)&3).
// ---------------------------------------------------------------------------
__device__ __forceinline__ void gemm_core(
    int bm, int bn,
    const uint16_t* __restrict__ A, const uint16_t* __restrict__ B,
    uint16_t (*As)[128 * 32], uint16_t (*Bs)[128 * 32], f32x4 acc[4][4]) {
  const int tid = threadIdx.x;
  const int lane = tid & 63, wave = tid >> 6;
  const int quad = lane >> 4, l16 = lane & 15;
  const int wr = (wave & 1) * 64, wc = (wave >> 1) * 64;
  const int sw = (l16 >> 1) & 3;               // read-side swizzle key

  auto stage = [&](int buf, int kt) {
#pragma unroll
    for (int it = 0; it < 2; ++it) {
      int L = it * 256 + tid;
      int r = L >> 2, c = L & 3;
      int gc = c ^ ((r >> 1) & 3);
      int ldsoff = (it * 256 + (tid & ~63)) * 16; // wave-uniform base
      gld16((const char*)A + ((size_t)(bm * 128 + r) * DIMM + kt * 32) * 2 + gc * 16,
            (char*)As[buf] + ldsoff);
      gld16((const char*)B + ((size_t)(bn * 128 + r) * DIMM + kt * 32) * 2 + gc * 16,
            (char*)Bs[buf] + ldsoff);
    }
  };

  stage(0, 0);
  for (int kt = 0; kt < DIMM / 32; ++kt) {
    const int cur = kt & 1;
    __syncthreads();                 // drains vmcnt(0): buf[cur] landed, buf[cur^1] free
    if (kt < DIMM / 32 - 1) stage(cur ^ 1, kt + 1);   // in flight through compute

    bf16x8 af[4], bfr[4];
#pragma unroll
    for (int i = 0; i < 4; ++i)
      af[i] = *(const bf16x8*)(As[cur] + (wr + i * 16 + l16) * 32 + ((quad ^ sw) * 8));
#pragma unroll
    for (int j = 0; j < 4; ++j)
      bfr[j] = *(const bf16x8*)(Bs[cur] + (wc + j * 16 + l16) * 32 + ((quad ^ sw) * 8));
    __builtin_amdgcn_s_setprio(1);
#pragma unroll
    for (int i = 0; i < 4; ++i)
#pragma unroll
      for (int j = 0; j < 4; ++j)
        acc[i][j] = mfma16(af[i], bfr[j], acc[i][j]);
    __builtin_amdgcn_s_setprio(0);
  }
}

// ---------------------------------------------------------------------------
// Kernel 2: QKV GEMM (M=8192, N=1536, K=512) with scatter epilogue.
// XCD swizzle: XCD x owns bm in [8x,8x+8) x all bn -> per-XCD L2 set =
// 1MB A-panel + 1.5MB B (resident), A re-reads become L2 hits.
// ---------------------------------------------------------------------------
__global__ __launch_bounds__(256, 4) void qkv_gemm(
    const uint16_t* __restrict__ xb, const uint16_t* __restrict__ wqb,
    uint16_t* __restrict__ qd, uint16_t* __restrict__ kd,
    uint16_t* __restrict__ vt) {
  __shared__ __align__(16) uint16_t As[2][128 * 32];
  __shared__ __align__(16) uint16_t Bs[2][128 * 32];
  const int lin = blockIdx.y * 64 + blockIdx.x;          // 0..767 (= 8*96)
  const int bm = (lin & 7) * 8 + ((lin >> 3) / 12);      // A-panel-major per XCD
  const int bn = (lin >> 3) % 12;
  f32x4 acc[4][4];
#pragma unroll
  for (int i = 0; i < 4; ++i)
#pragma unroll
    for (int j = 0; j < 4; ++j) acc[i][j] = f32x4{0.f, 0.f, 0.f, 0.f};

  gemm_core(bm, bn, xb, wqb, As, Bs, acc);

  const int lane = threadIdx.x & 63, wave = threadIdx.x >> 6;
  const int quad = lane >> 4, l16 = lane & 15;
  const int wr = (wave & 1) * 64, wc = (wave >> 1) * 64;
  const float qscale = 0.125f * 1.44269504f;   // fold log2(e) for exp2 softmax
#pragma unroll
  for (int i = 0; i < 4; ++i) {
    int m0 = bm * 128 + wr + i * 16 + quad * 4;          // 4 consecutive rows (r)
    int b = m0 >> 12, n0 = m0 & 4095;                    // block never crosses batch
#pragma unroll
    for (int j = 0; j < 4; ++j) {
      int jc = bn * 128 + wc + j * 16 + l16;
      int region = jc >> 9;                 // 0=q 1=k 2=v (uniform per frag)
      int h = (jc >> 6) & 7, hd = jc & 63;
      int bh = (b << 3) | h;
      if (region == 0) {
        uint32_t w01 = cvtpk(acc[i][j][0] * qscale, acc[i][j][1] * qscale);
        uint32_t w23 = cvtpk(acc[i][j][2] * qscale, acc[i][j][3] * qscale);
        size_t rb = ((size_t)bh * SEQ + n0) * HDIM + hd;
        qd[rb]            = (uint16_t)w01;
        qd[rb + HDIM]     = (uint16_t)(w01 >> 16);
        qd[rb + 2 * HDIM] = (uint16_t)w23;
        qd[rb + 3 * HDIM] = (uint16_t)(w23 >> 16);
      } else if (region == 1) {
        uint32_t w01 = cvtpk(acc[i][j][0], acc[i][j][1]);
        uint32_t w23 = cvtpk(acc[i][j][2], acc[i][j][3]);
        size_t rb = ((size_t)bh * SEQ + n0) * HDIM + hd;
        kd[rb]            = (uint16_t)w01;
        kd[rb + HDIM]     = (uint16_t)(w01 >> 16);
        kd[rb + 2 * HDIM] = (uint16_t)w23;
        kd[rb + 3 * HDIM] = (uint16_t)(w23 >> 16);
      } else {
        uint2 pk;                            // 4 consecutive n -> one 8B store
        pk.x = cvtpk(acc[i][j][0], acc[i][j][1]);
        pk.y = cvtpk(acc[i][j][2], acc[i][j][3]);
        *(uint2*)(vt + ((size_t)bh * HDIM + hd) * SEQ + n0) = pk;
      }
    }
  }
}

// ---------------------------------------------------------------------------
// Kernel 3: flash attention — r3-verified algebra at HALF block size.
// 256 threads = 4 waves = 2 pairs; pair p owns 32 q-rows (QBLK=64/block);
// khalf = wave&1 owns keys [khalf*32 .. +32) of each 64-key tile (KVBLK=64).
// LDS = dbuf K (2x8K) + dbuf V (2x8K) = 32KB -> 4 INDEPENDENT blocks/CU
// (same 16 waves/CU as before, but 4 desynced blocks instead of 2 ->
// cross-block overlap of {MFMA, trans/exp, VALU} phases; barrier groups
// shrink 8 -> 4 waves). Same per-key staging rate, same MFMA:VALU ratio.
// P stays in registers via permlane quad-exchange (r3-verified mapping with
// khalf*32 key base). ONE __syncthreads per K-tile, loads hidden a full phase.
// XCD decode: xcd = wid&7 hosts only bh in {xcd, xcd+8} (2MB L2-resident K/V).
// ---------------------------------------------------------------------------
__global__ __launch_bounds__(256, 4) void attn_kernel(
    const uint16_t* __restrict__ qd, const uint16_t* __restrict__ kd,
    const uint16_t* __restrict__ vt, uint16_t* __restrict__ ao) {
  __shared__ __align__(16) uint16_t Ks[2][64 * 64];   // [key][d], chunk c^=(row&7)
  __shared__ __align__(16) uint16_t Vs[2][64 * 64];   // [d][key], chunk c^=(row&7)

  const int tid = threadIdx.x, lane = tid & 63, wave = tid >> 6;  // wave 0..3
  const int quad = lane >> 4, l16 = lane & 15;
  const int pair = wave >> 1, khalf = wave & 1;
  // XCD-aware decode: blocks on XCD x serve only bh in {x, x+8}
  const int wid = blockIdx.x;
  const int xcd = wid & 7, slot = wid >> 3;          // slot 0..127
  const int bh = xcd + 8 * (slot & 1);
  const int qt = slot >> 1;                          // 0..63 (QBLK=64)
  const size_t base_qk = (size_t)bh * SEQ * HDIM;    // [bh][n][d]
  const size_t base_v  = (size_t)bh * HDIM * SEQ;    // [bh][d][n]
  const int sw7 = l16 & 7;

  // K-tile [64 keys][64 d] and V-tile [64 d][64 keys] have IDENTICAL
  // [64 rows][8 x 16B chunks] shape -> shared staging index math.
  auto stage = [&](int buf, int kt) {
#pragma unroll
    for (int it = 0; it < 2; ++it) {
      int L = it * 256 + tid;
      int ldsoff = (it * 256 + (tid & ~63)) * 16;
      int rk = L >> 3, ck = L & 7;
      int gck = ck ^ (rk & 7);
      gld16((const char*)kd + (base_qk + (size_t)(kt * 64 + rk) * HDIM) * 2 + gck * 16,
            (char*)Ks[buf] + ldsoff);
      gld16((const char*)vt + (base_v + (size_t)rk * SEQ + (size_t)kt * 64) * 2 + gck * 16,
            (char*)Vs[buf] + ldsoff);
    }
  };

  // Q fragments straight from global (one-time, L2-resident): B-op of K·Q^T
  bf16x8 qf[2][2];
#pragma unroll
  for (int it2 = 0; it2 < 2; ++it2)
#pragma unroll
    for (int kh = 0; kh < 2; ++kh)
      qf[it2][kh] = *(const bf16x8*)(qd + base_qk +
          (size_t)(qt * 64 + pair * 32 + it2 * 16 + l16) * HDIM + kh * 32 + quad * 8);

  f32x4 O[2][4];            // partial over this wave's keys
  float lsum[2] = {0.f, 0.f};
#pragma unroll
  for (int a = 0; a < 2; ++a)
#pragma unroll
    for (int d = 0; d < 4; ++d) O[a][d] = f32x4{0.f, 0.f, 0.f, 0.f};

  stage(0, 0);
  for (int kt = 0; kt < SEQ / 64; ++kt) {
    const int cur = kt & 1;
    __syncthreads();               // vmcnt(0): buf[cur] landed; buf[cur^1] free
    if (kt < SEQ / 64 - 1) stage(cur ^ 1, kt + 1);

    // K fragments for this wave's 32 keys (2 blocks of 16)
    bf16x8 kf[2][2];
#pragma unroll
    for (int jh = 0; jh < 2; ++jh) {
      int jf = khalf * 2 + jh;
      const uint16_t* krow = Ks[cur] + (jf * 16 + l16) * 64;
      kf[jh][0] = *(const bf16x8*)(krow + ((quad ^ sw7) * 8));
      kf[jh][1] = *(const bf16x8*)(krow + (((4 + quad) ^ sw7) * 8));
    }

    // S^T = K·Q^T : lane holds S^T[key = jf*16 + quad*4 + r][q = l16]
    f32x4 P[2][2];
    __builtin_amdgcn_s_setprio(1);
#pragma unroll
    for (int jh = 0; jh < 2; ++jh)
#pragma unroll
      for (int it2 = 0; it2 < 2; ++it2) {
        f32x4 s = f32x4{0.f, 0.f, 0.f, 0.f};
        s = mfma16(kf[jh][0], qf[it2][0], s);
        s = mfma16(kf[jh][1], qf[it2][1], s);
        P[jh][it2] = s;
      }
    __builtin_amdgcn_s_setprio(0);

    // exp2 + pack to bf16 pairs, all in registers
    uint32_t sp[2][2][2];          // [jh][it2][word]: keys {4q+2w, 4q+2w+1}
#pragma unroll
    for (int jh = 0; jh < 2; ++jh)
#pragma unroll
      for (int it2 = 0; it2 < 2; ++it2) {
        float p0 = EXP2F(P[jh][it2][0]);
        float p1 = EXP2F(P[jh][it2][1]);
        float p2 = EXP2F(P[jh][it2][2]);
        float p3 = EXP2F(P[jh][it2][3]);
        lsum[it2] += (p0 + p1) + (p2 + p3);
        sp[jh][it2][0] = cvtpk(p0, p1);
        sp[jh][it2][1] = cvtpk(p2, p3);
      }

    // quad-exchange: B-frag word t_w holds keys {8q+2w, 8q+2w+1} (32-key chunk)
    bf16x8 pb[2];                  // [it2]
#pragma unroll
    for (int it2 = 0; it2 < 2; ++it2) {
      uint32_t t0 = sp[0][it2][0], t2 = sp[1][it2][0];
      swap32(t0, t2); swap16(t0, t2);
      uint32_t t1 = sp[0][it2][1], t3 = sp[1][it2][1];
      swap32(t1, t3); swap16(t1, t3);
      u32x4 w = {t0, t1, t2, t3};
      pb[it2] = __builtin_bit_cast(bf16x8, w);
    }

    // O^T += V^T·P^T over this wave's 32 keys (one K=32 MFMA chunk)
    bf16x8 va[4];
#pragma unroll
    for (int dl = 0; dl < 4; ++dl)
      va[dl] = *(const bf16x8*)((const char*)Vs[cur] + (dl * 16 + l16) * 128 +
                                ((khalf * 4 + quad) ^ sw7) * 16);
    __builtin_amdgcn_s_setprio(1);
#pragma unroll
    for (int it2 = 0; it2 < 2; ++it2)
#pragma unroll
      for (int dl = 0; dl < 4; ++dl)
        O[it2][dl] = mfma16(va[dl], pb[it2], O[it2][dl]);
    __builtin_amdgcn_s_setprio(0);
  }

  // merge partial O / lsum across the wave pair, reusing Ks/Vs LDS
  __syncthreads();
  if (!(wave & 1)) {
    f32x4* ob = (f32x4*)((char*)Ks + pair * 8192);   // 8KB per pair (Ks = 16KB)
#pragma unroll
    for (int it2 = 0; it2 < 2; ++it2)
#pragma unroll
      for (int dl = 0; dl < 4; ++dl)
        ob[(it2 * 4 + dl) * 64 + lane] = O[it2][dl];
    float2* lb = (float2*)((char*)Vs + pair * 512);
    lb[lane] = make_float2(lsum[0], lsum[1]);
  }
  __syncthreads();
  if (wave & 1) {
    const f32x4* ob = (const f32x4*)((char*)Ks + pair * 8192);
    float2 lp = ((const float2*)((char*)Vs + pair * 512))[lane];
    lsum[0] += lp.x; lsum[1] += lp.y;
#pragma unroll
    for (int it2 = 0; it2 < 2; ++it2)
#pragma unroll
      for (int dl = 0; dl < 4; ++dl)
        O[it2][dl] += ob[(it2 * 4 + dl) * 64 + lane];

    const int b = bh >> 3, h = bh & 7;
#pragma unroll
    for (int it2 = 0; it2 < 2; ++it2) {
      float l = lsum[it2];
      l += __shfl_xor(l, 16);
      l += __shfl_xor(l, 32);
      float inv = 1.0f / l;
      int q = qt * 64 + pair * 32 + it2 * 16 + l16;
      size_t rowbase = ((size_t)(b * SEQ + q)) * DIMM + h * HDIM;
#pragma unroll
      for (int dl = 0; dl < 4; ++dl) {
        uint2 pk;
        pk.x = cvtpk(O[it2][dl][0] * inv, O[it2][dl][1] * inv);
        pk.y = cvtpk(O[it2][dl][2] * inv, O[it2][dl][3] * inv);
        *(uint2*)(ao + rowbase + dl * 16 + quad * 4) = pk;
      }
    }
  }
}

// ---------------------------------------------------------------------------
// Kernel 4: output projection (M=8192, N=512, K=512) + bias, fp32 out.
// 64x128 tiles -> 512 blocks = 2 blocks/CU (was 256 = 1/CU, latency-bound).
// 4 waves side-by-side: wave w owns cols [w*32, w*32+32), acc[4][2].
// LDS: A 2x4KB + B 2x8KB = 24KB. Bijective XCD decode: XCD x owns
// bm in [16x,16x+16) x all bn -> per-XCD 1MB A-panel + 0.5MB B (L2-resident).
// ---------------------------------------------------------------------------
__global__ __launch_bounds__(256, 4) void proj_gemm(
    const uint16_t* __restrict__ ao, const uint16_t* __restrict__ wpb,
    const float* __restrict__ bprj, float* __restrict__ out) {
  __shared__ __align__(16) uint16_t As[2][64 * 32];
  __shared__ __align__(16) uint16_t Bs[2][128 * 32];
  const int lin = blockIdx.y * 128 + blockIdx.x;   // 0..511, = HW linear id
  const int idx = lin >> 3;                        // 0..63
  const int bm = (lin & 7) * 16 + (idx >> 2);      // 0..127
  const int bn = idx & 3;                          // 0..3

  const int tid = threadIdx.x;
  const int lane = tid & 63, wave = tid >> 6;
  const int quad = lane >> 4, l16 = lane & 15;
  const int wc = wave * 32;
  const int sw = (l16 >> 1) & 3;

  f32x4 acc[4][2];
#pragma unroll
  for (int i = 0; i < 4; ++i)
#pragma unroll
    for (int j = 0; j < 2; ++j) acc[i][j] = f32x4{0.f, 0.f, 0.f, 0.f};

  auto stage = [&](int buf, int kt) {
    {
      int r = tid >> 2, c = tid & 3;               // A: 64 rows x 4 chunks
      int gc = c ^ ((r >> 1) & 3);
      int ldsoff = (tid & ~63) * 16;
      gld16((const char*)ao + ((size_t)(bm * 64 + r) * DIMM + kt * 32) * 2 + gc * 16,
            (char*)As[buf] + ldsoff);
    }
#pragma unroll
    for (int it = 0; it < 2; ++it) {               // B: 128 rows x 4 chunks
      int L = it * 256 + tid;
      int r = L >> 2, c = L & 3;
      int gc = c ^ ((r >> 1) & 3);
      int ldsoff = (it * 256 + (tid & ~63)) * 16;
      gld16((const char*)wpb + ((size_t)(bn * 128 + r) * DIMM + kt * 32) * 2 + gc * 16,
            (char*)Bs[buf] + ldsoff);
    }
  };

  stage(0, 0);
  for (int kt = 0; kt < DIMM / 32; ++kt) {
    const int cur = kt & 1;
    __syncthreads();
    if (kt < DIMM / 32 - 1) stage(cur ^ 1, kt + 1);

    bf16x8 af[4], bfr[2];
#pragma unroll
    for (int i = 0; i < 4; ++i)
      af[i] = *(const bf16x8*)(As[cur] + (i * 16 + l16) * 32 + ((quad ^ sw) * 8));
#pragma unroll
    for (int j = 0; j < 2; ++j)
      bfr[j] = *(const bf16x8*)(Bs[cur] + (wc + j * 16 + l16) * 32 + ((quad ^ sw) * 8));
    __builtin_amdgcn_s_setprio(1);
#pragma unroll
    for (int i = 0; i < 4; ++i)
#pragma unroll
      for (int j = 0; j < 2; ++j)
        acc[i][j] = mfma16(af[i], bfr[j], acc[i][j]);
    __builtin_amdgcn_s_setprio(0);
  }

#pragma unroll
  for (int i = 0; i < 4; ++i) {
    int m0 = bm * 64 + i * 16 + quad * 4;
#pragma unroll
    for (int j = 0; j < 2; ++j) {
      int jc = bn * 128 + wc + j * 16 + l16;
      float bias = bprj[jc];
#pragma unroll
      for (int r = 0; r < 4; ++r)
        out[(size_t)(m0 + r) * DIMM + jc] = acc[i][j][r] + bias;
    }
  }
}

// ---------------------------------------------------------------------------
extern "C" void kernel_launch(void* const* d_in, const int* in_sizes, int n_in,
                              void* d_out, int out_size, void* d_ws, size_t ws_size,
                              hipStream_t stream) {
  const float* x     = (const float*)d_in[0];
  const float* wqkv  = (const float*)d_in[1];
  const float* wproj = (const float*)d_in[2];
  const float* bproj = (const float*)d_in[3];

  char* ws = (char*)d_ws;
  uint16_t* xb  = (uint16_t*)(ws + 0);          //  8,388,608  x bf16 [8192][512]
  uint16_t* wqb = (uint16_t*)(ws + 8388608);    //  1,572,864  w_qkv bf16 [1536][512]
  uint16_t* wpb = (uint16_t*)(ws + 9961472);    //    524,288  w_proj bf16 [512][512]
  uint16_t* qd  = (uint16_t*)(ws + 10485760);   //  8,388,608  q bf16 [16][4096][64] (scaled)
  uint16_t* kd  = (uint16_t*)(ws + 18874368);   //  8,388,608  k bf16 [16][4096][64]
  uint16_t* vt  = (uint16_t*)(ws + 27262976);   //  8,388,608  v bf16 [16][64][4096]
  uint16_t* ao  = (uint16_t*)(ws + 35651584);   //  8,388,608  attn out bf16 [8192][512]

  cvt_kernel<<<(X4 + Q4 + P4) / 256, 256, 0, stream>>>(x, wqkv, wproj, xb, wqb, wpb);
  qkv_gemm<<<dim3(64, 12), 256, 0, stream>>>(xb, wqb, qd, kd, vt);
  attn_kernel<<<1024, 256, 0, stream>>>(qd, kd, vt, ao);
  proj_gemm<<<dim3(128, 4), 256, 0, stream>>>(ao, wpb, bproj, (float*)d_out);
}

// Round 7
// 185.917 us; speedup vs baseline: 1.0404x; 1.0404x over previous
//
#include <hip/hip_runtime.h>
#include <stdint.h>

// Problem constants
#define SEQ   4096
#define DIMM  512
#define HDIM  64
#define NH    8
#define ROWS  8192          // B*N = 2*4096
#define QKVN  1536          // 3*DIM

typedef __attribute__((ext_vector_type(8))) __bf16 bf16x8;   // MFMA A/B frag (4 VGPRs)
typedef __attribute__((ext_vector_type(4))) float  f32x4;    // MFMA C/D frag
typedef __attribute__((ext_vector_type(4))) uint32_t u32x4;

// packed fp32x2 -> bf16x2 (RNE) in ONE VALU op. low16 = bf16(lo), hi16 = bf16(hi).
__device__ __forceinline__ uint32_t cvtpk(float lo, float hi) {
  uint32_t w;
  asm("v_cvt_pk_bf16_f32 %0, %1, %2" : "=v"(w) : "v"(lo), "v"(hi));
  return w;
}

// gfx950 cross-lane half-swaps (VALU pipe, NOT LDS).
__device__ __forceinline__ void swap32(uint32_t& a, uint32_t& b) {
  asm("v_permlane32_swap_b32 %0, %1" : "+v"(a), "+v"(b));
}
__device__ __forceinline__ void swap16(uint32_t& a, uint32_t& b) {
  asm("v_permlane16_swap_b32 %0, %1" : "+v"(a), "+v"(b));
}

__device__ __forceinline__ f32x4 mfma16(bf16x8 a, bf16x8 b, f32x4 c) {
  return __builtin_amdgcn_mfma_f32_16x16x32_bf16(a, b, c, 0, 0, 0);
}

#if __has_builtin(__builtin_amdgcn_exp2f)
#define EXP2F(x) __builtin_amdgcn_exp2f(x)
#else
#define EXP2F(x) exp2f(x)
#endif

// async global->LDS, 16B per lane. LDS dest is wave-uniform base + lane*16;
// the GLOBAL address is per-lane free -> we use it to store XOR-swizzled tiles.
__device__ __forceinline__ void gld16(const void* g, void* l) {
  __builtin_amdgcn_global_load_lds(
      (const __attribute__((address_space(1))) uint32_t*)g,
      (__attribute__((address_space(3))) uint32_t*)l, 16, 0, 0);
}

// ---------------------------------------------------------------------------
// Kernel 1: fp32 -> bf16 conversion of x, w_qkv, w_proj (one grid, 3 segments)
// ---------------------------------------------------------------------------
#define X4  (ROWS * DIMM / 4)    // 1048576
#define Q4  (QKVN * DIMM / 4)    // 196608
#define P4  (DIMM * DIMM / 4)    // 65536

__global__ __launch_bounds__(256) void cvt_kernel(
    const float* __restrict__ x, const float* __restrict__ wq,
    const float* __restrict__ wp, uint16_t* __restrict__ xb,
    uint16_t* __restrict__ wqb, uint16_t* __restrict__ wpb) {
  int idx = blockIdx.x * 256 + threadIdx.x;    // float4 index
  const float* src; uint16_t* dst; int i4;
  if (idx < X4)            { src = x;  dst = xb;  i4 = idx; }
  else if (idx < X4 + Q4)  { src = wq; dst = wqb; i4 = idx - X4; }
  else                     { src = wp; dst = wpb; i4 = idx - X4 - Q4; }
  float4 v = ((const float4*)src)[i4];
  uint2 o;
  o.x = cvtpk(v.x, v.y);
  o.y = cvtpk(v.z, v.w);
  ((uint2*)dst)[i4] = o;
}

// ---------------------------------------------------------------------------
// Shared GEMM core: C[128x128] = A[128xK] * B[128xK]^T  (both row-major, K=512)
// 256 threads = 4 waves in 2x2, each wave 64x64 via 4x4 MFMA frags.
// Double-buffered LDS [2][128][32] bf16; ONE __syncthreads per K-step.
// SWAP=false: lane holds C[m=quad*4+r][jc=l16]  (rows of A on quad axis)
// SWAP=true : operands swapped -> lane holds C[jc=quad*4+r][m=l16]
//   (legal: A and B operands share the same lane->index layout; verified by
//    the attn S^T=K*Q^T formulation). Used to make q/k epilogue stores 8B-wide.
// ---------------------------------------------------------------------------
template <bool SWAP>
__device__ __forceinline__ void gemm_core(
    int bm, int bn,
    const uint16_t* __restrict__ A, const uint16_t* __restrict__ B,
    uint16_t (*As)[128 * 32], uint16_t (*Bs)[128 * 32], f32x4 acc[4][4]) {
  const int tid = threadIdx.x;
  const int lane = tid & 63, wave = tid >> 6;
  const int quad = lane >> 4, l16 = lane & 15;
  const int wr = (wave & 1) * 64, wc = (wave >> 1) * 64;
  const int sw = (l16 >> 1) & 3;               // read-side swizzle key

  auto stage = [&](int buf, int kt) {
#pragma unroll
    for (int it = 0; it < 2; ++it) {
      int L = it * 256 + tid;
      int r = L >> 2, c = L & 3;
      int gc = c ^ ((r >> 1) & 3);
      int ldsoff = (it * 256 + (tid & ~63)) * 16; // wave-uniform base
      gld16((const char*)A + ((size_t)(bm * 128 + r) * DIMM + kt * 32) * 2 + gc * 16,
            (char*)As[buf] + ldsoff);
      gld16((const char*)B + ((size_t)(bn * 128 + r) * DIMM + kt * 32) * 2 + gc * 16,
            (char*)Bs[buf] + ldsoff);
    }
  };

  stage(0, 0);
  for (int kt = 0; kt < DIMM / 32; ++kt) {
    const int cur = kt & 1;
    __syncthreads();                 // drains vmcnt(0): buf[cur] landed, buf[cur^1] free
    if (kt < DIMM / 32 - 1) stage(cur ^ 1, kt + 1);   // in flight through compute

    bf16x8 af[4], bfr[4];
#pragma unroll
    for (int i = 0; i < 4; ++i)
      af[i] = *(const bf16x8*)(As[cur] + (wr + i * 16 + l16) * 32 + ((quad ^ sw) * 8));
#pragma unroll
    for (int j = 0; j < 4; ++j)
      bfr[j] = *(const bf16x8*)(Bs[cur] + (wc + j * 16 + l16) * 32 + ((quad ^ sw) * 8));
    __builtin_amdgcn_s_setprio(1);
#pragma unroll
    for (int i = 0; i < 4; ++i)
#pragma unroll
      for (int j = 0; j < 4; ++j) {
        if constexpr (SWAP)
          acc[i][j] = mfma16(bfr[j], af[i], acc[i][j]);
        else
          acc[i][j] = mfma16(af[i], bfr[j], acc[i][j]);
      }
    __builtin_amdgcn_s_setprio(0);
  }
}

// ---------------------------------------------------------------------------
// Kernel 2: QKV GEMM (M=8192, N=1536, K=512) with scatter epilogue.
// XCD swizzle: XCD x owns bm in [8x,8x+8) x all bn (L2-resident A panel).
// q/k blocks (bn<8) use SWAP=true: lane holds 4 consecutive hd for one n
//   -> ONE 8B ushort4 store per frag (was 4x 2B scalar scatter).
// v blocks (bn>=8) keep SWAP=false: 8B store along n (already optimal).
// ---------------------------------------------------------------------------
__global__ __launch_bounds__(256, 4) void qkv_gemm(
    const uint16_t* __restrict__ xb, const uint16_t* __restrict__ wqb,
    uint16_t* __restrict__ qd, uint16_t* __restrict__ kd,
    uint16_t* __restrict__ vt) {
  __shared__ __align__(16) uint16_t As[2][128 * 32];
  __shared__ __align__(16) uint16_t Bs[2][128 * 32];
  const int lin = blockIdx.y * 64 + blockIdx.x;          // 0..767 (= 8*96)
  const int bm = (lin & 7) * 8 + ((lin >> 3) / 12);      // A-panel-major per XCD
  const int bn = (lin >> 3) % 12;
  f32x4 acc[4][4];
#pragma unroll
  for (int i = 0; i < 4; ++i)
#pragma unroll
    for (int j = 0; j < 4; ++j) acc[i][j] = f32x4{0.f, 0.f, 0.f, 0.f};

  const int lane = threadIdx.x & 63, wave = threadIdx.x >> 6;
  const int quad = lane >> 4, l16 = lane & 15;
  const int wr = (wave & 1) * 64, wc = (wave >> 1) * 64;
  const float qscale = 0.125f * 1.44269504f;   // fold log2(e) for exp2 softmax

  if (bn < 8) {
    gemm_core<true>(bm, bn, xb, wqb, As, Bs, acc);
    // SWAP layout: C[jc = bn*128+wc+j*16+quad*4+r][m = bm*128+wr+i*16+l16]
    uint16_t* dst = (bn < 4) ? qd : kd;
    const float qs = (bn < 4) ? qscale : 1.0f;
#pragma unroll
    for (int i = 0; i < 4; ++i) {
      int m = bm * 128 + wr + i * 16 + l16;
      int b = m >> 12, n0 = m & 4095;
#pragma unroll
      for (int j = 0; j < 4; ++j) {
        int jc0 = bn * 128 + wc + j * 16 + quad * 4;   // 4 consecutive hd
        int h = (jc0 >> 6) & 7, hd0 = jc0 & 63;
        int bh = (b << 3) | h;
        uint2 pk;
        pk.x = cvtpk(acc[i][j][0] * qs, acc[i][j][1] * qs);
        pk.y = cvtpk(acc[i][j][2] * qs, acc[i][j][3] * qs);
        *(uint2*)(dst + ((size_t)bh * SEQ + n0) * HDIM + hd0) = pk;
      }
    }
  } else {
    gemm_core<false>(bm, bn, xb, wqb, As, Bs, acc);
    // original layout: C[m = ...+quad*4+r][jc = ...+l16]; v innermost dim = n
#pragma unroll
    for (int i = 0; i < 4; ++i) {
      int m0 = bm * 128 + wr + i * 16 + quad * 4;      // 4 consecutive rows (n)
      int b = m0 >> 12, n0 = m0 & 4095;
#pragma unroll
      for (int j = 0; j < 4; ++j) {
        int jc = bn * 128 + wc + j * 16 + l16;
        int h = (jc >> 6) & 7, hd = jc & 63;
        int bh = (b << 3) | h;
        uint2 pk;                            // 4 consecutive n -> one 8B store
        pk.x = cvtpk(acc[i][j][0], acc[i][j][1]);
        pk.y = cvtpk(acc[i][j][2], acc[i][j][3]);
        *(uint2*)(vt + ((size_t)bh * HDIM + hd) * SEQ + n0) = pk;
      }
    }
  }
}

// ---------------------------------------------------------------------------
// Kernel 3: flash attention (r5/r3 structure — verified 87us, no spill).
// S^T formulation, key-split wave pairs; P in-register via permlane swaps;
// dbuf K/V, ONE __syncthreads per K-tile; XCD-aware bh decode.
// LDS = 2x16K (K) + 2x16K (V) = 64KB; 2 blocks/CU -> 16 waves/CU.
// r4 lesson: 2-tile P carry spills at the 128-VGPR cap. r6 lesson: halving
// the block (KVBLK=64) doubles per-key fixed overhead -> slower. Keep as-is.
// ---------------------------------------------------------------------------
__global__ __launch_bounds__(512, 4) void attn_kernel(
    const uint16_t* __restrict__ qd, const uint16_t* __restrict__ kd,
    const uint16_t* __restrict__ vt, uint16_t* __restrict__ ao) {
  __shared__ __align__(16) uint16_t Ks[2][128 * 64];   // [key][d], chunk c^=(row&7)
  __shared__ __align__(16) uint16_t Vs[2][64 * 128];   // [d][key], chunk c^=(row&15)

  const int tid = threadIdx.x, lane = tid & 63, wave = tid >> 6;  // wave 0..7
  const int quad = lane >> 4, l16 = lane & 15;
  const int pair = wave >> 1, khalf = wave & 1;
  // XCD-aware decode: blocks on XCD x serve only bh in {x, x+8}
  const int wid = blockIdx.x;
  const int xcd = wid & 7, slot = wid >> 3;          // slot 0..63
  const int bh = xcd + 8 * (slot & 1);
  const int qt = slot >> 1;                          // 0..31
  const size_t base_qk = (size_t)bh * SEQ * HDIM;    // [bh][n][d]
  const size_t base_v  = (size_t)bh * HDIM * SEQ;    // [bh][d][n]
  const int sw7 = l16 & 7;

  auto stage = [&](int buf, int kt) {
#pragma unroll
    for (int it = 0; it < 2; ++it) {
      int L = it * 512 + tid;
      int ldsoff = (it * 512 + (tid & ~63)) * 16;
      int rk = L >> 3, ck = L & 7;
      int gck = ck ^ (rk & 7);
      gld16((const char*)kd + (base_qk + (size_t)(kt * 128 + rk) * HDIM) * 2 + gck * 16,
            (char*)Ks[buf] + ldsoff);
      int rv = L >> 4, cv = L & 15;
      int gcv = cv ^ (rv & 15);
      gld16((const char*)vt + (base_v + (size_t)rv * SEQ + (size_t)kt * 128) * 2 + gcv * 16,
            (char*)Vs[buf] + ldsoff);
    }
  };

  // Q fragments straight from global (one-time, L2-resident): B-op of K·Q^T
  bf16x8 qf[2][2];
#pragma unroll
  for (int it2 = 0; it2 < 2; ++it2)
#pragma unroll
    for (int kh = 0; kh < 2; ++kh)
      qf[it2][kh] = *(const bf16x8*)(qd + base_qk +
          (size_t)(qt * 128 + pair * 32 + it2 * 16 + l16) * HDIM + kh * 32 + quad * 8);

  f32x4 O[2][4];            // partial over this wave's keys
  float lsum[2] = {0.f, 0.f};
#pragma unroll
  for (int a = 0; a < 2; ++a)
#pragma unroll
    for (int d = 0; d < 4; ++d) O[a][d] = f32x4{0.f, 0.f, 0.f, 0.f};

  stage(0, 0);
  for (int kt = 0; kt < SEQ / 128; ++kt) {
    const int cur = kt & 1;
    __syncthreads();               // vmcnt(0): buf[cur] landed; buf[cur^1] free
    if (kt < SEQ / 128 - 1) stage(cur ^ 1, kt + 1);

    // K fragments for this wave's 64 keys (4 blocks of 16)
    bf16x8 kf[4][2];
#pragma unroll
    for (int jh = 0; jh < 4; ++jh) {
      int jf = khalf * 4 + jh;
      const uint16_t* krow = Ks[cur] + (jf * 16 + l16) * 64;
      kf[jh][0] = *(const bf16x8*)(krow + ((quad ^ sw7) * 8));
      kf[jh][1] = *(const bf16x8*)(krow + (((4 + quad) ^ sw7) * 8));
    }

    // S^T = K·Q^T : lane holds S^T[key=jf*16+quad*4+r][q=l16]
    f32x4 P[4][2];
    __builtin_amdgcn_s_setprio(1);
#pragma unroll
    for (int jh = 0; jh < 4; ++jh)
#pragma unroll
      for (int it2 = 0; it2 < 2; ++it2) {
        f32x4 s = f32x4{0.f, 0.f, 0.f, 0.f};
        s = mfma16(kf[jh][0], qf[it2][0], s);
        s = mfma16(kf[jh][1], qf[it2][1], s);
        P[jh][it2] = s;
      }
    __builtin_amdgcn_s_setprio(0);

    // exp2 + pack to bf16 pairs, all in registers
    uint32_t sp[4][2][2];          // [jh][it2][word]: keys {4q+2w, 4q+2w+1}
#pragma unroll
    for (int jh = 0; jh < 4; ++jh)
#pragma unroll
      for (int it2 = 0; it2 < 2; ++it2) {
        float p0 = EXP2F(P[jh][it2][0]);
        float p1 = EXP2F(P[jh][it2][1]);
        float p2 = EXP2F(P[jh][it2][2]);
        float p3 = EXP2F(P[jh][it2][3]);
        lsum[it2] += (p0 + p1) + (p2 + p3);
        sp[jh][it2][0] = cvtpk(p0, p1);
        sp[jh][it2][1] = cvtpk(p2, p3);
      }

    // quad-exchange: B-frag word t_w holds keys {8q+2w,8q+2w+1} of the kp chunk
    bf16x8 pb[2][2];               // [kp][it2]
#pragma unroll
    for (int kp = 0; kp < 2; ++kp)
#pragma unroll
      for (int it2 = 0; it2 < 2; ++it2) {
        uint32_t t0 = sp[2 * kp][it2][0], t2 = sp[2 * kp + 1][it2][0];
        swap32(t0, t2); swap16(t0, t2);
        uint32_t t1 = sp[2 * kp][it2][1], t3 = sp[2 * kp + 1][it2][1];
        swap32(t1, t3); swap16(t1, t3);
        u32x4 w = {t0, t1, t2, t3};
        pb[kp][it2] = __builtin_bit_cast(bf16x8, w);
      }

    // O^T += V^T·P^T per 32-key chunk (va loaded per-kp to cap registers)
#pragma unroll
    for (int kp = 0; kp < 2; ++kp) {
      bf16x8 va[4];
#pragma unroll
      for (int dl = 0; dl < 4; ++dl)
        va[dl] = *(const bf16x8*)((const char*)Vs[cur] + (dl * 16 + l16) * 256 +
                                  (((khalf * 8 + kp * 4 + quad) ^ l16) & 15) * 16);
      __builtin_amdgcn_s_setprio(1);
#pragma unroll
      for (int it2 = 0; it2 < 2; ++it2)
#pragma unroll
        for (int dl = 0; dl < 4; ++dl)
          O[it2][dl] = mfma16(va[dl], pb[kp][it2], O[it2][dl]);
      __builtin_amdgcn_s_setprio(0);
    }
  }

  // merge partial O / lsum across the wave pair, reusing Ks/Vs LDS
  __syncthreads();
  if (!(wave & 1)) {
    f32x4* ob = (f32x4*)((char*)Ks + pair * 8192);   // 8KB per pair
#pragma unroll
    for (int it2 = 0; it2 < 2; ++it2)
#pragma unroll
      for (int dl = 0; dl < 4; ++dl)
        ob[(it2 * 4 + dl) * 64 + lane] = O[it2][dl];
    float2* lb = (float2*)((char*)Vs + pair * 512);
    lb[lane] = make_float2(lsum[0], lsum[1]);
  }
  __syncthreads();
  if (wave & 1) {
    const f32x4* ob = (const f32x4*)((char*)Ks + pair * 8192);
    float2 lp = ((const float2*)((char*)Vs + pair * 512))[lane];
    lsum[0] += lp.x; lsum[1] += lp.y;
#pragma unroll
    for (int it2 = 0; it2 < 2; ++it2)
#pragma unroll
      for (int dl = 0; dl < 4; ++dl)
        O[it2][dl] += ob[(it2 * 4 + dl) * 64 + lane];

    const int b = bh >> 3, h = bh & 7;
#pragma unroll
    for (int it2 = 0; it2 < 2; ++it2) {
      float l = lsum[it2];
      l += __shfl_xor(l, 16);
      l += __shfl_xor(l, 32);
      float inv = 1.0f / l;
      int q = qt * 128 + pair * 32 + it2 * 16 + l16;
      size_t rowbase = ((size_t)(b * SEQ + q)) * DIMM + h * HDIM;
#pragma unroll
      for (int dl = 0; dl < 4; ++dl) {
        uint2 pk;
        pk.x = cvtpk(O[it2][dl][0] * inv, O[it2][dl][1] * inv);
        pk.y = cvtpk(O[it2][dl][2] * inv, O[it2][dl][3] * inv);
        *(uint2*)(ao + rowbase + dl * 16 + quad * 4) = pk;
      }
    }
  }
}

// ---------------------------------------------------------------------------
// Kernel 4: output projection (M=8192, N=512, K=512) + bias, fp32 out.
// 64x128 tiles, 512 blocks = 2 blocks/CU; SWAPPED operands: lane holds
// 4 consecutive output cols for one row -> float4 16B stores (was 32x 4B).
// Bijective XCD decode: XCD x owns bm in [16x,16x+16) x all bn.
// ---------------------------------------------------------------------------
__global__ __launch_bounds__(256, 4) void proj_gemm(
    const uint16_t* __restrict__ ao, const uint16_t* __restrict__ wpb,
    const float* __restrict__ bprj, float* __restrict__ out) {
  __shared__ __align__(16) uint16_t As[2][64 * 32];
  __shared__ __align__(16) uint16_t Bs[2][128 * 32];
  const int lin = blockIdx.y * 128 + blockIdx.x;   // 0..511, = HW linear id
  const int idx = lin >> 3;                        // 0..63
  const int bm = (lin & 7) * 16 + (idx >> 2);      // 0..127
  const int bn = idx & 3;                          // 0..3

  const int tid = threadIdx.x;
  const int lane = tid & 63, wave = tid >> 6;
  const int quad = lane >> 4, l16 = lane & 15;
  const int wc = wave * 32;
  const int sw = (l16 >> 1) & 3;

  f32x4 acc[4][2];
#pragma unroll
  for (int i = 0; i < 4; ++i)
#pragma unroll
    for (int j = 0; j < 2; ++j) acc[i][j] = f32x4{0.f, 0.f, 0.f, 0.f};

  auto stage = [&](int buf, int kt) {
    {
      int r = tid >> 2, c = tid & 3;               // A: 64 rows x 4 chunks
      int gc = c ^ ((r >> 1) & 3);
      int ldsoff = (tid & ~63) * 16;
      gld16((const char*)ao + ((size_t)(bm * 64 + r) * DIMM + kt * 32) * 2 + gc * 16,
            (char*)As[buf] + ldsoff);
    }
#pragma unroll
    for (int it = 0; it < 2; ++it) {               // B: 128 rows x 4 chunks
      int L = it * 256 + tid;
      int r = L >> 2, c = L & 3;
      int gc = c ^ ((r >> 1) & 3);
      int ldsoff = (it * 256 + (tid & ~63)) * 16;
      gld16((const char*)wpb + ((size_t)(bn * 128 + r) * DIMM + kt * 32) * 2 + gc * 16,
            (char*)Bs[buf] + ldsoff);
    }
  };

  stage(0, 0);
  for (int kt = 0; kt < DIMM / 32; ++kt) {
    const int cur = kt & 1;
    __syncthreads();
    if (kt < DIMM / 32 - 1) stage(cur ^ 1, kt + 1);

    bf16x8 af[4], bfr[2];
#pragma unroll
    for (int i = 0; i < 4; ++i)
      af[i] = *(const bf16x8*)(As[cur] + (i * 16 + l16) * 32 + ((quad ^ sw) * 8));
#pragma unroll
    for (int j = 0; j < 2; ++j)
      bfr[j] = *(const bf16x8*)(Bs[cur] + (wc + j * 16 + l16) * 32 + ((quad ^ sw) * 8));
    __builtin_amdgcn_s_setprio(1);
#pragma unroll
    for (int i = 0; i < 4; ++i)
#pragma unroll
      for (int j = 0; j < 2; ++j)
        acc[i][j] = mfma16(bfr[j], af[i], acc[i][j]);   // SWAPPED operands
    __builtin_amdgcn_s_setprio(0);
  }

  // SWAP layout: C[jc = bn*128+wc+j*16+quad*4+r][m = bm*64+i*16+l16]
#pragma unroll
  for (int i = 0; i < 4; ++i) {
    int m = bm * 64 + i * 16 + l16;
#pragma unroll
    for (int j = 0; j < 2; ++j) {
      int jc0 = bn * 128 + wc + j * 16 + quad * 4;     // 4 consecutive cols
      float4 b4 = *(const float4*)(bprj + jc0);
      float4 o;
      o.x = acc[i][j][0] + b4.x;
      o.y = acc[i][j][1] + b4.y;
      o.z = acc[i][j][2] + b4.z;
      o.w = acc[i][j][3] + b4.w;
      *(float4*)(out + (size_t)m * DIMM + jc0) = o;    // one 16B store
    }
  }
}

// ---------------------------------------------------------------------------
extern "C" void kernel_launch(void* const* d_in, const int* in_sizes, int n_in,
                              void* d_out, int out_size, void* d_ws, size_t ws_size,
                              hipStream_t stream) {
  const float* x     = (const float*)d_in[0];
  const float* wqkv  = (const float*)d_in[1];
  const float* wproj = (const float*)d_in[2];
  const float* bproj = (const float*)d_in[3];

  char* ws = (char*)d_ws;
  uint16_t* xb  = (uint16_t*)(ws + 0);          //  8,388,608  x bf16 [8192][512]
  uint16_t* wqb = (uint16_t*)(ws + 8388608);    //  1,572,864  w_qkv bf16 [1536][512]
  uint16_t* wpb = (uint16_t*)(ws + 9961472);    //    524,288  w_proj bf16 [512][512]
  uint16_t* qd  = (uint16_t*)(ws + 10485760);   //  8,388,608  q bf16 [16][4096][64] (scaled)
  uint16_t* kd  = (uint16_t*)(ws + 18874368);   //  8,388,608  k bf16 [16][4096][64]
  uint16_t* vt  = (uint16_t*)(ws + 27262976);   //  8,388,608  v bf16 [16][64][4096]
  uint16_t* ao  = (uint16_t*)(ws + 35651584);   //  8,388,608  attn out bf16 [8192][512]

  cvt_kernel<<<(X4 + Q4 + P4) / 256, 256, 0, stream>>>(x, wqkv, wproj, xb, wqb, wpb);
  qkv_gemm<<<dim3(64, 12), 256, 0, stream>>>(xb, wqb, qd, kd, vt);
  attn_kernel<<<512, 512, 0, stream>>>(qd, kd, vt, ao);
  proj_gemm<<<dim3(128, 4), 256, 0, stream>>>(ao, wpb, bproj, (float*)d_out);
}

// Round 8
// 179.476 us; speedup vs baseline: 1.0777x; 1.0359x over previous
//
#include <hip/hip_runtime.h>
#include <stdint.h>

// Problem constants
#define SEQ   4096
#define DIMM  512
#define HDIM  64
#define NH    8
#define ROWS  8192          // B*N = 2*4096
#define QKVN  1536          // 3*DIM

typedef __attribute__((ext_vector_type(8))) __bf16 bf16x8;   // MFMA A/B frag (4 VGPRs)
typedef __attribute__((ext_vector_type(4))) float  f32x4;    // MFMA C/D frag
typedef __attribute__((ext_vector_type(4))) uint32_t u32x4;

// packed fp32x2 -> bf16x2 (RNE) in ONE VALU op. low16 = bf16(lo), hi16 = bf16(hi).
__device__ __forceinline__ uint32_t cvtpk(float lo, float hi) {
  uint32_t w;
  asm("v_cvt_pk_bf16_f32 %0, %1, %2" : "=v"(w) : "v"(lo), "v"(hi));
  return w;
}

// gfx950 cross-lane half-swaps (VALU pipe, NOT LDS).
__device__ __forceinline__ void swap32(uint32_t& a, uint32_t& b) {
  asm("v_permlane32_swap_b32 %0, %1" : "+v"(a), "+v"(b));
}
__device__ __forceinline__ void swap16(uint32_t& a, uint32_t& b) {
  asm("v_permlane16_swap_b32 %0, %1" : "+v"(a), "+v"(b));
}

__device__ __forceinline__ f32x4 mfma16(bf16x8 a, bf16x8 b, f32x4 c) {
  return __builtin_amdgcn_mfma_f32_16x16x32_bf16(a, b, c, 0, 0, 0);
}

#if __has_builtin(__builtin_amdgcn_exp2f)
#define EXP2F(x) __builtin_amdgcn_exp2f(x)
#else
#define EXP2F(x) exp2f(x)
#endif

// async global->LDS, 16B per lane. LDS dest is wave-uniform base + lane*16;
// the GLOBAL address is per-lane free -> we use it to store XOR-swizzled tiles.
__device__ __forceinline__ void gld16(const void* g, void* l) {
  __builtin_amdgcn_global_load_lds(
      (const __attribute__((address_space(1))) uint32_t*)g,
      (__attribute__((address_space(3))) uint32_t*)l, 16, 0, 0);
}

// ---------------------------------------------------------------------------
// Kernel 1: fp32 -> bf16 conversion of x, w_qkv, w_proj (one grid, 3 segments)
// ---------------------------------------------------------------------------
#define X4  (ROWS * DIMM / 4)    // 1048576
#define Q4  (QKVN * DIMM / 4)    // 196608
#define P4  (DIMM * DIMM / 4)    // 65536

__global__ __launch_bounds__(256) void cvt_kernel(
    const float* __restrict__ x, const float* __restrict__ wq,
    const float* __restrict__ wp, uint16_t* __restrict__ xb,
    uint16_t* __restrict__ wqb, uint16_t* __restrict__ wpb) {
  int idx = blockIdx.x * 256 + threadIdx.x;    // float4 index
  const float* src; uint16_t* dst; int i4;
  if (idx < X4)            { src = x;  dst = xb;  i4 = idx; }
  else if (idx < X4 + Q4)  { src = wq; dst = wqb; i4 = idx - X4; }
  else                     { src = wp; dst = wpb; i4 = idx - X4 - Q4; }
  float4 v = ((const float4*)src)[i4];
  uint2 o;
  o.x = cvtpk(v.x, v.y);
  o.y = cvtpk(v.z, v.w);
  ((uint2*)dst)[i4] = o;
}

// ---------------------------------------------------------------------------
// Shared GEMM core: C[128x128] = A[128xK] * B[128xK]^T  (both row-major, K=512)
// 256 threads = 4 waves in 2x2, each wave 64x64 via 4x4 MFMA frags.
// Double-buffered LDS [2][128][32] bf16; ONE __syncthreads per K-step.
// bm/bn passed in (XCD-swizzled by caller). swizzle c' = c ^ ((r>>1)&3).
// ---------------------------------------------------------------------------
__device__ __forceinline__ void gemm_core(
    int bm, int bn,
    const uint16_t* __restrict__ A, const uint16_t* __restrict__ B,
    uint16_t (*As)[128 * 32], uint16_t (*Bs)[128 * 32], f32x4 acc[4][4]) {
  const int tid = threadIdx.x;
  const int lane = tid & 63, wave = tid >> 6;
  const int quad = lane >> 4, l16 = lane & 15;
  const int wr = (wave & 1) * 64, wc = (wave >> 1) * 64;
  const int sw = (l16 >> 1) & 3;               // read-side swizzle key

  auto stage = [&](int buf, int kt) {
#pragma unroll
    for (int it = 0; it < 2; ++it) {
      int L = it * 256 + tid;
      int r = L >> 2, c = L & 3;
      int gc = c ^ ((r >> 1) & 3);
      int ldsoff = (it * 256 + (tid & ~63)) * 16; // wave-uniform base
      gld16((const char*)A + ((size_t)(bm * 128 + r) * DIMM + kt * 32) * 2 + gc * 16,
            (char*)As[buf] + ldsoff);
      gld16((const char*)B + ((size_t)(bn * 128 + r) * DIMM + kt * 32) * 2 + gc * 16,
            (char*)Bs[buf] + ldsoff);
    }
  };

  stage(0, 0);
  for (int kt = 0; kt < DIMM / 32; ++kt) {
    const int cur = kt & 1;
    __syncthreads();                 // drains vmcnt(0): buf[cur] landed, buf[cur^1] free
    if (kt < DIMM / 32 - 1) stage(cur ^ 1, kt + 1);   // in flight through compute

    bf16x8 af[4], bfr[4];
#pragma unroll
    for (int i = 0; i < 4; ++i)
      af[i] = *(const bf16x8*)(As[cur] + (wr + i * 16 + l16) * 32 + ((quad ^ sw) * 8));
#pragma unroll
    for (int j = 0; j < 4; ++j)
      bfr[j] = *(const bf16x8*)(Bs[cur] + (wc + j * 16 + l16) * 32 + ((quad ^ sw) * 8));
    __builtin_amdgcn_s_setprio(1);
#pragma unroll
    for (int i = 0; i < 4; ++i)
#pragma unroll
      for (int j = 0; j < 4; ++j)
        acc[i][j] = mfma16(af[i], bfr[j], acc[i][j]);
    __builtin_amdgcn_s_setprio(0);
  }
}

// ---------------------------------------------------------------------------
// Kernel 2: QKV GEMM (M=8192, N=1536, K=512) with scatter epilogue.
// XCD swizzle: XCD x owns bm in [8x,8x+8) x all bn -> per-XCD L2 set =
// 1MB A-panel + 1.5MB B (resident), A re-reads become L2 hits.
// (r7 lesson: SWAP-operand epilogue stores = worse line coalescing; reverted.)
// ---------------------------------------------------------------------------
__global__ __launch_bounds__(256, 4) void qkv_gemm(
    const uint16_t* __restrict__ xb, const uint16_t* __restrict__ wqb,
    uint16_t* __restrict__ qd, uint16_t* __restrict__ kd,
    uint16_t* __restrict__ vt) {
  __shared__ __align__(16) uint16_t As[2][128 * 32];
  __shared__ __align__(16) uint16_t Bs[2][128 * 32];
  const int lin = blockIdx.y * 64 + blockIdx.x;          // 0..767 (= 8*96)
  const int bm = (lin & 7) * 8 + ((lin >> 3) / 12);      // A-panel-major per XCD
  const int bn = (lin >> 3) % 12;
  f32x4 acc[4][4];
#pragma unroll
  for (int i = 0; i < 4; ++i)
#pragma unroll
    for (int j = 0; j < 4; ++j) acc[i][j] = f32x4{0.f, 0.f, 0.f, 0.f};

  gemm_core(bm, bn, xb, wqb, As, Bs, acc);

  const int lane = threadIdx.x & 63, wave = threadIdx.x >> 6;
  const int quad = lane >> 4, l16 = lane & 15;
  const int wr = (wave & 1) * 64, wc = (wave >> 1) * 64;
  const float qscale = 0.125f * 1.44269504f;   // fold log2(e) for exp2 softmax
#pragma unroll
  for (int i = 0; i < 4; ++i) {
    int m0 = bm * 128 + wr + i * 16 + quad * 4;          // 4 consecutive rows (r)
    int b = m0 >> 12, n0 = m0 & 4095;                    // block never crosses batch
#pragma unroll
    for (int j = 0; j < 4; ++j) {
      int jc = bn * 128 + wc + j * 16 + l16;
      int region = jc >> 9;                 // 0=q 1=k 2=v (uniform per frag)
      int h = (jc >> 6) & 7, hd = jc & 63;
      int bh = (b << 3) | h;
      if (region == 0) {
        uint32_t w01 = cvtpk(acc[i][j][0] * qscale, acc[i][j][1] * qscale);
        uint32_t w23 = cvtpk(acc[i][j][2] * qscale, acc[i][j][3] * qscale);
        size_t rb = ((size_t)bh * SEQ + n0) * HDIM + hd;
        qd[rb]            = (uint16_t)w01;
        qd[rb + HDIM]     = (uint16_t)(w01 >> 16);
        qd[rb + 2 * HDIM] = (uint16_t)w23;
        qd[rb + 3 * HDIM] = (uint16_t)(w23 >> 16);
      } else if (region == 1) {
        uint32_t w01 = cvtpk(acc[i][j][0], acc[i][j][1]);
        uint32_t w23 = cvtpk(acc[i][j][2], acc[i][j][3]);
        size_t rb = ((size_t)bh * SEQ + n0) * HDIM + hd;
        kd[rb]            = (uint16_t)w01;
        kd[rb + HDIM]     = (uint16_t)(w01 >> 16);
        kd[rb + 2 * HDIM] = (uint16_t)w23;
        kd[rb + 3 * HDIM] = (uint16_t)(w23 >> 16);
      } else {
        uint2 pk;                            // 4 consecutive n -> one 8B store
        pk.x = cvtpk(acc[i][j][0], acc[i][j][1]);
        pk.y = cvtpk(acc[i][j][2], acc[i][j][3]);
        *(uint2*)(vt + ((size_t)bh * HDIM + hd) * SEQ + n0) = pk;
      }
    }
  }
}

// ---------------------------------------------------------------------------
// Kernel 3: flash attention (r5 structure) + lsum-via-ones-MFMA:
// the softmax denominator is a column-sum of P^T, computed by
// mfma16(ones, pb) on the matrix pipe (33% utilized) instead of 24
// v_add_f32/kt on the VALU (48% utilized). Lacc[it2] accumulates the
// wave's full 64-key sum -> the epilogue cross-quad shfl reduce is gone;
// only the pair-partner merge remains. Denominator now uses the SAME
// bf16-rounded p as the numerator (weights sum exactly to 1).
// LDS = dbuf K (2x16K) + dbuf V (2x16K) = 64KB; 2 blocks/CU.
// ---------------------------------------------------------------------------
__global__ __launch_bounds__(512, 4) void attn_kernel(
    const uint16_t* __restrict__ qd, const uint16_t* __restrict__ kd,
    const uint16_t* __restrict__ vt, uint16_t* __restrict__ ao) {
  __shared__ __align__(16) uint16_t Ks[2][128 * 64];   // [key][d], chunk c^=(row&7)
  __shared__ __align__(16) uint16_t Vs[2][64 * 128];   // [d][key], chunk c^=(row&15)

  const int tid = threadIdx.x, lane = tid & 63, wave = tid >> 6;  // wave 0..7
  const int quad = lane >> 4, l16 = lane & 15;
  const int pair = wave >> 1, khalf = wave & 1;
  // XCD-aware decode: blocks on XCD x serve only bh in {x, x+8}
  const int wid = blockIdx.x;
  const int xcd = wid & 7, slot = wid >> 3;          // slot 0..63
  const int bh = xcd + 8 * (slot & 1);
  const int qt = slot >> 1;                          // 0..31
  const size_t base_qk = (size_t)bh * SEQ * HDIM;    // [bh][n][d]
  const size_t base_v  = (size_t)bh * HDIM * SEQ;    // [bh][d][n]
  const int sw7 = l16 & 7;

  auto stage = [&](int buf, int kt) {
#pragma unroll
    for (int it = 0; it < 2; ++it) {
      int L = it * 512 + tid;
      int ldsoff = (it * 512 + (tid & ~63)) * 16;
      int rk = L >> 3, ck = L & 7;
      int gck = ck ^ (rk & 7);
      gld16((const char*)kd + (base_qk + (size_t)(kt * 128 + rk) * HDIM) * 2 + gck * 16,
            (char*)Ks[buf] + ldsoff);
      int rv = L >> 4, cv = L & 15;
      int gcv = cv ^ (rv & 15);
      gld16((const char*)vt + (base_v + (size_t)rv * SEQ + (size_t)kt * 128) * 2 + gcv * 16,
            (char*)Vs[buf] + ldsoff);
    }
  };

  // Q fragments straight from global (one-time, L2-resident): B-op of K·Q^T
  bf16x8 qf[2][2];
#pragma unroll
  for (int it2 = 0; it2 < 2; ++it2)
#pragma unroll
    for (int kh = 0; kh < 2; ++kh)
      qf[it2][kh] = *(const bf16x8*)(qd + base_qk +
          (size_t)(qt * 128 + pair * 32 + it2 * 16 + l16) * HDIM + kh * 32 + quad * 8);

  // bf16 1.0 x8 constant: A-operand of the lsum MFMA
  const u32x4 onesw = {0x3F803F80u, 0x3F803F80u, 0x3F803F80u, 0x3F803F80u};
  const bf16x8 onesf = __builtin_bit_cast(bf16x8, onesw);

  f32x4 O[2][4];            // partial over this wave's keys
  f32x4 Lacc[2];            // lsum accumulator: col=l16=q, rows duplicated
#pragma unroll
  for (int a = 0; a < 2; ++a) {
    Lacc[a] = f32x4{0.f, 0.f, 0.f, 0.f};
#pragma unroll
    for (int d = 0; d < 4; ++d) O[a][d] = f32x4{0.f, 0.f, 0.f, 0.f};
  }

  stage(0, 0);
  for (int kt = 0; kt < SEQ / 128; ++kt) {
    const int cur = kt & 1;
    __syncthreads();               // vmcnt(0): buf[cur] landed; buf[cur^1] free
    if (kt < SEQ / 128 - 1) stage(cur ^ 1, kt + 1);

    // K fragments for this wave's 64 keys (4 blocks of 16)
    bf16x8 kf[4][2];
#pragma unroll
    for (int jh = 0; jh < 4; ++jh) {
      int jf = khalf * 4 + jh;
      const uint16_t* krow = Ks[cur] + (jf * 16 + l16) * 64;
      kf[jh][0] = *(const bf16x8*)(krow + ((quad ^ sw7) * 8));
      kf[jh][1] = *(const bf16x8*)(krow + (((4 + quad) ^ sw7) * 8));
    }

    // S^T = K·Q^T : lane holds S^T[key=jf*16+quad*4+r][q=l16]
    f32x4 P[4][2];
    __builtin_amdgcn_s_setprio(1);
#pragma unroll
    for (int jh = 0; jh < 4; ++jh)
#pragma unroll
      for (int it2 = 0; it2 < 2; ++it2) {
        f32x4 s = f32x4{0.f, 0.f, 0.f, 0.f};
        s = mfma16(kf[jh][0], qf[it2][0], s);
        s = mfma16(kf[jh][1], qf[it2][1], s);
        P[jh][it2] = s;
      }
    __builtin_amdgcn_s_setprio(0);

    // exp2 + pack to bf16 pairs, all in registers (no scalar lsum adds)
    uint32_t sp[4][2][2];          // [jh][it2][word]: keys {4q+2w, 4q+2w+1}
#pragma unroll
    for (int jh = 0; jh < 4; ++jh)
#pragma unroll
      for (int it2 = 0; it2 < 2; ++it2) {
        float p0 = EXP2F(P[jh][it2][0]);
        float p1 = EXP2F(P[jh][it2][1]);
        float p2 = EXP2F(P[jh][it2][2]);
        float p3 = EXP2F(P[jh][it2][3]);
        sp[jh][it2][0] = cvtpk(p0, p1);
        sp[jh][it2][1] = cvtpk(p2, p3);
      }

    // quad-exchange: B-frag word t_w holds keys {8q+2w,8q+2w+1} of the kp chunk
    bf16x8 pb[2][2];               // [kp][it2]
#pragma unroll
    for (int kp = 0; kp < 2; ++kp)
#pragma unroll
      for (int it2 = 0; it2 < 2; ++it2) {
        uint32_t t0 = sp[2 * kp][it2][0], t2 = sp[2 * kp + 1][it2][0];
        swap32(t0, t2); swap16(t0, t2);
        uint32_t t1 = sp[2 * kp][it2][1], t3 = sp[2 * kp + 1][it2][1];
        swap32(t1, t3); swap16(t1, t3);
        u32x4 w = {t0, t1, t2, t3};
        pb[kp][it2] = __builtin_bit_cast(bf16x8, w);
      }

    // O^T += V^T·P^T per 32-key chunk; lsum += ones·P^T on the same pipe
#pragma unroll
    for (int kp = 0; kp < 2; ++kp) {
      bf16x8 va[4];
#pragma unroll
      for (int dl = 0; dl < 4; ++dl)
        va[dl] = *(const bf16x8*)((const char*)Vs[cur] + (dl * 16 + l16) * 256 +
                                  (((khalf * 8 + kp * 4 + quad) ^ l16) & 15) * 16);
      __builtin_amdgcn_s_setprio(1);
#pragma unroll
      for (int it2 = 0; it2 < 2; ++it2) {
        Lacc[it2] = mfma16(onesf, pb[kp][it2], Lacc[it2]);
#pragma unroll
        for (int dl = 0; dl < 4; ++dl)
          O[it2][dl] = mfma16(va[dl], pb[kp][it2], O[it2][dl]);
      }
      __builtin_amdgcn_s_setprio(0);
    }
  }

  // per-wave lsum: every lane's Lacc[it2][0] = sum over this wave's 64 keys
  float lsum[2] = {Lacc[0][0], Lacc[1][0]};

  // merge partial O / lsum across the wave pair, reusing Ks/Vs LDS
  __syncthreads();
  if (!(wave & 1)) {
    f32x4* ob = (f32x4*)((char*)Ks + pair * 8192);   // 8KB per pair
#pragma unroll
    for (int it2 = 0; it2 < 2; ++it2)
#pragma unroll
      for (int dl = 0; dl < 4; ++dl)
        ob[(it2 * 4 + dl) * 64 + lane] = O[it2][dl];
    float2* lb = (float2*)((char*)Vs + pair * 512);
    lb[lane] = make_float2(lsum[0], lsum[1]);
  }
  __syncthreads();
  if (wave & 1) {
    const f32x4* ob = (const f32x4*)((char*)Ks + pair * 8192);
    float2 lp = ((const float2*)((char*)Vs + pair * 512))[lane];
    lsum[0] += lp.x; lsum[1] += lp.y;
#pragma unroll
    for (int it2 = 0; it2 < 2; ++it2)
#pragma unroll
      for (int dl = 0; dl < 4; ++dl)
        O[it2][dl] += ob[(it2 * 4 + dl) * 64 + lane];

    const int b = bh >> 3, h = bh & 7;
#pragma unroll
    for (int it2 = 0; it2 < 2; ++it2) {
      float inv = 1.0f / lsum[it2];        // lane-complete: no shfl reduce needed
      int q = qt * 128 + pair * 32 + it2 * 16 + l16;
      size_t rowbase = ((size_t)(b * SEQ + q)) * DIMM + h * HDIM;
#pragma unroll
      for (int dl = 0; dl < 4; ++dl) {
        uint2 pk;
        pk.x = cvtpk(O[it2][dl][0] * inv, O[it2][dl][1] * inv);
        pk.y = cvtpk(O[it2][dl][2] * inv, O[it2][dl][3] * inv);
        *(uint2*)(ao + rowbase + dl * 16 + quad * 4) = pk;
      }
    }
  }
}

// ---------------------------------------------------------------------------
// Kernel 4: output projection (M=8192, N=512, K=512) + bias, fp32 out.
// 64x128 tiles -> 512 blocks = 2 blocks/CU. 4 waves side-by-side: wave w
// owns cols [w*32, w*32+32), acc[4][2]. LDS: A 2x4KB + B 2x8KB = 24KB.
// Bijective XCD decode: XCD x owns bm in [16x,16x+16) x all bn.
// ---------------------------------------------------------------------------
__global__ __launch_bounds__(256, 4) void proj_gemm(
    const uint16_t* __restrict__ ao, const uint16_t* __restrict__ wpb,
    const float* __restrict__ bprj, float* __restrict__ out) {
  __shared__ __align__(16) uint16_t As[2][64 * 32];
  __shared__ __align__(16) uint16_t Bs[2][128 * 32];
  const int lin = blockIdx.y * 128 + blockIdx.x;   // 0..511, = HW linear id
  const int idx = lin >> 3;                        // 0..63
  const int bm = (lin & 7) * 16 + (idx >> 2);      // 0..127
  const int bn = idx & 3;                          // 0..3

  const int tid = threadIdx.x;
  const int lane = tid & 63, wave = tid >> 6;
  const int quad = lane >> 4, l16 = lane & 15;
  const int wc = wave * 32;
  const int sw = (l16 >> 1) & 3;

  f32x4 acc[4][2];
#pragma unroll
  for (int i = 0; i < 4; ++i)
#pragma unroll
    for (int j = 0; j < 2; ++j) acc[i][j] = f32x4{0.f, 0.f, 0.f, 0.f};

  auto stage = [&](int buf, int kt) {
    {
      int r = tid >> 2, c = tid & 3;               // A: 64 rows x 4 chunks
      int gc = c ^ ((r >> 1) & 3);
      int ldsoff = (tid & ~63) * 16;
      gld16((const char*)ao + ((size_t)(bm * 64 + r) * DIMM + kt * 32) * 2 + gc * 16,
            (char*)As[buf] + ldsoff);
    }
#pragma unroll
    for (int it = 0; it < 2; ++it) {               // B: 128 rows x 4 chunks
      int L = it * 256 + tid;
      int r = L >> 2, c = L & 3;
      int gc = c ^ ((r >> 1) & 3);
      int ldsoff = (it * 256 + (tid & ~63)) * 16;
      gld16((const char*)wpb + ((size_t)(bn * 128 + r) * DIMM + kt * 32) * 2 + gc * 16,
            (char*)Bs[buf] + ldsoff);
    }
  };

  stage(0, 0);
  for (int kt = 0; kt < DIMM / 32; ++kt) {
    const int cur = kt & 1;
    __syncthreads();
    if (kt < DIMM / 32 - 1) stage(cur ^ 1, kt + 1);

    bf16x8 af[4], bfr[2];
#pragma unroll
    for (int i = 0; i < 4; ++i)
      af[i] = *(const bf16x8*)(As[cur] + (i * 16 + l16) * 32 + ((quad ^ sw) * 8));
#pragma unroll
    for (int j = 0; j < 2; ++j)
      bfr[j] = *(const bf16x8*)(Bs[cur] + (wc + j * 16 + l16) * 32 + ((quad ^ sw) * 8));
    __builtin_amdgcn_s_setprio(1);
#pragma unroll
    for (int i = 0; i < 4; ++i)
#pragma unroll
      for (int j = 0; j < 2; ++j)
        acc[i][j] = mfma16(af[i], bfr[j], acc[i][j]);
    __builtin_amdgcn_s_setprio(0);
  }

#pragma unroll
  for (int i = 0; i < 4; ++i) {
    int m0 = bm * 64 + i * 16 + quad * 4;
#pragma unroll
    for (int j = 0; j < 2; ++j) {
      int jc = bn * 128 + wc + j * 16 + l16;
      float bias = bprj[jc];
#pragma unroll
      for (int r = 0; r < 4; ++r)
        out[(size_t)(m0 + r) * DIMM + jc] = acc[i][j][r] + bias;
    }
  }
}

// ---------------------------------------------------------------------------
extern "C" void kernel_launch(void* const* d_in, const int* in_sizes, int n_in,
                              void* d_out, int out_size, void* d_ws, size_t ws_size,
                              hipStream_t stream) {
  const float* x     = (const float*)d_in[0];
  const float* wqkv  = (const float*)d_in[1];
  const float* wproj = (const float*)d_in[2];
  const float* bproj = (const float*)d_in[3];

  char* ws = (char*)d_ws;
  uint16_t* xb  = (uint16_t*)(ws + 0);          //  8,388,608  x bf16 [8192][512]
  uint16_t* wqb = (uint16_t*)(ws + 8388608);    //  1,572,864  w_qkv bf16 [1536][512]
  uint16_t* wpb = (uint16_t*)(ws + 9961472);    //    524,288  w_proj bf16 [512][512]
  uint16_t* qd  = (uint16_t*)(ws + 10485760);   //  8,388,608  q bf16 [16][4096][64] (scaled)
  uint16_t* kd  = (uint16_t*)(ws + 18874368);   //  8,388,608  k bf16 [16][4096][64]
  uint16_t* vt  = (uint16_t*)(ws + 27262976);   //  8,388,608  v bf16 [16][64][4096]
  uint16_t* ao  = (uint16_t*)(ws + 35651584);   //  8,388,608  attn out bf16 [8192][512]

  cvt_kernel<<<(X4 + Q4 + P4) / 256, 256, 0, stream>>>(x, wqkv, wproj, xb, wqb, wpb);
  qkv_gemm<<<dim3(64, 12), 256, 0, stream>>>(xb, wqb, qd, kd, vt);
  attn_kernel<<<512, 512, 0, stream>>>(qd, kd, vt, ao);
  proj_gemm<<<dim3(128, 4), 256, 0, stream>>>(ao, wpb, bproj, (float*)d_out);
}

// Round 9
// 175.169 us; speedup vs baseline: 1.1042x; 1.0246x over previous
//
#include <hip/hip_runtime.h>
#include <stdint.h>

// Problem constants
#define SEQ   4096
#define DIMM  512
#define HDIM  64
#define NH    8
#define ROWS  8192          // B*N = 2*4096
#define QKVN  1536          // 3*DIM

typedef __attribute__((ext_vector_type(8))) __bf16 bf16x8;   // MFMA A/B frag (4 VGPRs)
typedef __attribute__((ext_vector_type(4))) float  f32x4;    // MFMA C/D frag
typedef __attribute__((ext_vector_type(4))) uint32_t u32x4;

// packed fp32x2 -> bf16x2 (RNE) in ONE VALU op. low16 = bf16(lo), hi16 = bf16(hi).
__device__ __forceinline__ uint32_t cvtpk(float lo, float hi) {
  uint32_t w;
  asm("v_cvt_pk_bf16_f32 %0, %1, %2" : "=v"(w) : "v"(lo), "v"(hi));
  return w;
}

// gfx950 cross-lane half-swaps (VALU pipe, NOT LDS).
__device__ __forceinline__ void swap32(uint32_t& a, uint32_t& b) {
  asm("v_permlane32_swap_b32 %0, %1" : "+v"(a), "+v"(b));
}
__device__ __forceinline__ void swap16(uint32_t& a, uint32_t& b) {
  asm("v_permlane16_swap_b32 %0, %1" : "+v"(a), "+v"(b));
}

__device__ __forceinline__ f32x4 mfma16(bf16x8 a, bf16x8 b, f32x4 c) {
  return __builtin_amdgcn_mfma_f32_16x16x32_bf16(a, b, c, 0, 0, 0);
}

#if __has_builtin(__builtin_amdgcn_exp2f)
#define EXP2F(x) __builtin_amdgcn_exp2f(x)
#else
#define EXP2F(x) exp2f(x)
#endif

// async global->LDS, 16B per lane. LDS dest is wave-uniform base + lane*16;
// the GLOBAL address is per-lane free -> we use it to store XOR-swizzled tiles.
__device__ __forceinline__ void gld16(const void* g, void* l) {
  __builtin_amdgcn_global_load_lds(
      (const __attribute__((address_space(1))) uint32_t*)g,
      (__attribute__((address_space(3))) uint32_t*)l, 16, 0, 0);
}

// ---------------------------------------------------------------------------
// Kernel 1: fp32 -> bf16 conversion of WEIGHTS only (w_qkv, w_proj).
// x conversion is fused into qkv_gemm's A-staging (reg-stage + cvt_pk).
// ---------------------------------------------------------------------------
#define Q4  (QKVN * DIMM / 4)    // 196608
#define P4  (DIMM * DIMM / 4)    // 65536

__global__ __launch_bounds__(256) void cvt_kernel(
    const float* __restrict__ wq, const float* __restrict__ wp,
    uint16_t* __restrict__ wqb, uint16_t* __restrict__ wpb) {
  int idx = blockIdx.x * 256 + threadIdx.x;    // float4 index
  const float* src; uint16_t* dst; int i4;
  if (idx < Q4) { src = wq; dst = wqb; i4 = idx; }
  else          { src = wp; dst = wpb; i4 = idx - Q4; }
  float4 v = ((const float4*)src)[i4];
  uint2 o;
  o.x = cvtpk(v.x, v.y);
  o.y = cvtpk(v.z, v.w);
  ((uint2*)dst)[i4] = o;
}

// ---------------------------------------------------------------------------
// Kernel 2: QKV GEMM (M=8192, N=1536, K=512), A read DIRECTLY from fp32 x:
// reg-stage (2x float4 per 16B-chunk) -> cvt_pk -> ds_write_b128 into the
// SAME swizzled LDS layout the gld16 path produced. Loads issued right after
// the barrier; convert+write placed after the MFMA block (latency hidden).
// B staged via gld16 from pre-converted wqb. launch_bounds (256,3): grid is
// exactly 3 blocks/CU, so relax the VGPR cap to fit the +16 staged regs.
// XCD swizzle: XCD x owns bm in [8x,8x+8) x all bn (A panel L2-resident).
// ---------------------------------------------------------------------------
__global__ __launch_bounds__(256, 3) void qkv_gemm(
    const float* __restrict__ x, const uint16_t* __restrict__ wqb,
    uint16_t* __restrict__ qd, uint16_t* __restrict__ kd,
    uint16_t* __restrict__ vt) {
  __shared__ __align__(16) uint16_t As[2][128 * 32];
  __shared__ __align__(16) uint16_t Bs[2][128 * 32];
  const int lin = blockIdx.y * 64 + blockIdx.x;          // 0..767 (= 8*96)
  const int bm = (lin & 7) * 8 + ((lin >> 3) / 12);      // A-panel-major per XCD
  const int bn = (lin >> 3) % 12;

  const int tid = threadIdx.x;
  const int lane = tid & 63, wave = tid >> 6;
  const int quad = lane >> 4, l16 = lane & 15;
  const int wr = (wave & 1) * 64, wc = (wave >> 1) * 64;
  const int sw = (l16 >> 1) & 3;               // read-side swizzle key

  f32x4 acc[4][4];
#pragma unroll
  for (int i = 0; i < 4; ++i)
#pragma unroll
    for (int j = 0; j < 4; ++j) acc[i][j] = f32x4{0.f, 0.f, 0.f, 0.f};

  auto stageB = [&](int buf, int kt) {
#pragma unroll
    for (int it = 0; it < 2; ++it) {
      int L = it * 256 + tid;
      int r = L >> 2, c = L & 3;
      int gc = c ^ ((r >> 1) & 3);
      int ldsoff = (it * 256 + (tid & ~63)) * 16;
      gld16((const char*)wqb + ((size_t)(bn * 128 + r) * DIMM + kt * 32) * 2 + gc * 16,
            (char*)Bs[buf] + ldsoff);
    }
  };
  // A: thread L owns row r=L>>2, chunk c=L&3 (8 bf16 / 16B LDS slot = 32B fp32)
  auto loadA = [&](int kt, float4 (&av)[4]) {
#pragma unroll
    for (int it = 0; it < 2; ++it) {
      int L = it * 256 + tid;
      int r = L >> 2, c = L & 3;
      int gc = c ^ ((r >> 1) & 3);
      const float* src = x + (size_t)(bm * 128 + r) * DIMM + kt * 32 + gc * 8;
      av[it * 2]     = *(const float4*)(src);
      av[it * 2 + 1] = *(const float4*)(src + 4);
    }
  };
  auto writeA = [&](int buf, float4 (&av)[4]) {
#pragma unroll
    for (int it = 0; it < 2; ++it) {
      int L = it * 256 + tid;
      u32x4 w;
      w.x = cvtpk(av[it * 2].x,     av[it * 2].y);
      w.y = cvtpk(av[it * 2].z,     av[it * 2].w);
      w.z = cvtpk(av[it * 2 + 1].x, av[it * 2 + 1].y);
      w.w = cvtpk(av[it * 2 + 1].z, av[it * 2 + 1].w);
      *(u32x4*)((char*)As[buf] + L * 16) = w;   // ds_write_b128, same slot gld16 used
    }
  };

  float4 av[4];
  loadA(0, av); writeA(0, av); stageB(0, 0);
  for (int kt = 0; kt < DIMM / 32; ++kt) {
    const int cur = kt & 1;
    __syncthreads();               // drains vm+lgkm: B(kt) landed, A(kt) written
    if (kt < DIMM / 32 - 1) { loadA(kt + 1, av); stageB(cur ^ 1, kt + 1); }

    bf16x8 af[4], bfr[4];
#pragma unroll
    for (int i = 0; i < 4; ++i)
      af[i] = *(const bf16x8*)(As[cur] + (wr + i * 16 + l16) * 32 + ((quad ^ sw) * 8));
#pragma unroll
    for (int j = 0; j < 4; ++j)
      bfr[j] = *(const bf16x8*)(Bs[cur] + (wc + j * 16 + l16) * 32 + ((quad ^ sw) * 8));
    __builtin_amdgcn_s_setprio(1);
#pragma unroll
    for (int i = 0; i < 4; ++i)
#pragma unroll
      for (int j = 0; j < 4; ++j)
        acc[i][j] = mfma16(af[i], bfr[j], acc[i][j]);
    __builtin_amdgcn_s_setprio(0);
    if (kt < DIMM / 32 - 1) writeA(cur ^ 1, av);   // f32 loads landed under MFMA
  }

  const float qscale = 0.125f * 1.44269504f;   // fold log2(e) for exp2 softmax
#pragma unroll
  for (int i = 0; i < 4; ++i) {
    int m0 = bm * 128 + wr + i * 16 + quad * 4;          // 4 consecutive rows (r)
    int b = m0 >> 12, n0 = m0 & 4095;                    // block never crosses batch
#pragma unroll
    for (int j = 0; j < 4; ++j) {
      int jc = bn * 128 + wc + j * 16 + l16;
      int region = jc >> 9;                 // 0=q 1=k 2=v (uniform per frag)
      int h = (jc >> 6) & 7, hd = jc & 63;
      int bh = (b << 3) | h;
      if (region == 0) {
        uint32_t w01 = cvtpk(acc[i][j][0] * qscale, acc[i][j][1] * qscale);
        uint32_t w23 = cvtpk(acc[i][j][2] * qscale, acc[i][j][3] * qscale);
        size_t rb = ((size_t)bh * SEQ + n0) * HDIM + hd;
        qd[rb]            = (uint16_t)w01;
        qd[rb + HDIM]     = (uint16_t)(w01 >> 16);
        qd[rb + 2 * HDIM] = (uint16_t)w23;
        qd[rb + 3 * HDIM] = (uint16_t)(w23 >> 16);
      } else if (region == 1) {
        uint32_t w01 = cvtpk(acc[i][j][0], acc[i][j][1]);
        uint32_t w23 = cvtpk(acc[i][j][2], acc[i][j][3]);
        size_t rb = ((size_t)bh * SEQ + n0) * HDIM + hd;
        kd[rb]            = (uint16_t)w01;
        kd[rb + HDIM]     = (uint16_t)(w01 >> 16);
        kd[rb + 2 * HDIM] = (uint16_t)w23;
        kd[rb + 3 * HDIM] = (uint16_t)(w23 >> 16);
      } else {
        uint2 pk;                            // 4 consecutive n -> one 8B store
        pk.x = cvtpk(acc[i][j][0], acc[i][j][1]);
        pk.y = cvtpk(acc[i][j][2], acc[i][j][3]);
        *(uint2*)(vt + ((size_t)bh * HDIM + hd) * SEQ + n0) = pk;
      }
    }
  }
}

// ---------------------------------------------------------------------------
// Kernel 3: flash attention (r8 verified: 83.5us). S^T formulation, key-split
// wave pairs; P in-register via permlane swaps; lsum via ones-MFMA on the
// matrix pipe (no scalar adds, no epilogue shfl reduce); dbuf K/V, ONE
// __syncthreads per K-tile; XCD-aware bh decode.
// LDS = 2x16K (K) + 2x16K (V) = 64KB; 2 blocks/CU.
// ---------------------------------------------------------------------------
__global__ __launch_bounds__(512, 4) void attn_kernel(
    const uint16_t* __restrict__ qd, const uint16_t* __restrict__ kd,
    const uint16_t* __restrict__ vt, uint16_t* __restrict__ ao) {
  __shared__ __align__(16) uint16_t Ks[2][128 * 64];   // [key][d], chunk c^=(row&7)
  __shared__ __align__(16) uint16_t Vs[2][64 * 128];   // [d][key], chunk c^=(row&15)

  const int tid = threadIdx.x, lane = tid & 63, wave = tid >> 6;  // wave 0..7
  const int quad = lane >> 4, l16 = lane & 15;
  const int pair = wave >> 1, khalf = wave & 1;
  // XCD-aware decode: blocks on XCD x serve only bh in {x, x+8}
  const int wid = blockIdx.x;
  const int xcd = wid & 7, slot = wid >> 3;          // slot 0..63
  const int bh = xcd + 8 * (slot & 1);
  const int qt = slot >> 1;                          // 0..31
  const size_t base_qk = (size_t)bh * SEQ * HDIM;    // [bh][n][d]
  const size_t base_v  = (size_t)bh * HDIM * SEQ;    // [bh][d][n]
  const int sw7 = l16 & 7;

  auto stage = [&](int buf, int kt) {
#pragma unroll
    for (int it = 0; it < 2; ++it) {
      int L = it * 512 + tid;
      int ldsoff = (it * 512 + (tid & ~63)) * 16;
      int rk = L >> 3, ck = L & 7;
      int gck = ck ^ (rk & 7);
      gld16((const char*)kd + (base_qk + (size_t)(kt * 128 + rk) * HDIM) * 2 + gck * 16,
            (char*)Ks[buf] + ldsoff);
      int rv = L >> 4, cv = L & 15;
      int gcv = cv ^ (rv & 15);
      gld16((const char*)vt + (base_v + (size_t)rv * SEQ + (size_t)kt * 128) * 2 + gcv * 16,
            (char*)Vs[buf] + ldsoff);
    }
  };

  // Q fragments straight from global (one-time, L2-resident): B-op of K·Q^T
  bf16x8 qf[2][2];
#pragma unroll
  for (int it2 = 0; it2 < 2; ++it2)
#pragma unroll
    for (int kh = 0; kh < 2; ++kh)
      qf[it2][kh] = *(const bf16x8*)(qd + base_qk +
          (size_t)(qt * 128 + pair * 32 + it2 * 16 + l16) * HDIM + kh * 32 + quad * 8);

  // bf16 1.0 x8 constant: A-operand of the lsum MFMA
  const u32x4 onesw = {0x3F803F80u, 0x3F803F80u, 0x3F803F80u, 0x3F803F80u};
  const bf16x8 onesf = __builtin_bit_cast(bf16x8, onesw);

  f32x4 O[2][4];            // partial over this wave's keys
  f32x4 Lacc[2];            // lsum accumulator: col=l16=q, rows duplicated
#pragma unroll
  for (int a = 0; a < 2; ++a) {
    Lacc[a] = f32x4{0.f, 0.f, 0.f, 0.f};
#pragma unroll
    for (int d = 0; d < 4; ++d) O[a][d] = f32x4{0.f, 0.f, 0.f, 0.f};
  }

  stage(0, 0);
  for (int kt = 0; kt < SEQ / 128; ++kt) {
    const int cur = kt & 1;
    __syncthreads();               // vmcnt(0): buf[cur] landed; buf[cur^1] free
    if (kt < SEQ / 128 - 1) stage(cur ^ 1, kt + 1);

    // K fragments for this wave's 64 keys (4 blocks of 16)
    bf16x8 kf[4][2];
#pragma unroll
    for (int jh = 0; jh < 4; ++jh) {
      int jf = khalf * 4 + jh;
      const uint16_t* krow = Ks[cur] + (jf * 16 + l16) * 64;
      kf[jh][0] = *(const bf16x8*)(krow + ((quad ^ sw7) * 8));
      kf[jh][1] = *(const bf16x8*)(krow + (((4 + quad) ^ sw7) * 8));
    }

    // S^T = K·Q^T : lane holds S^T[key=jf*16+quad*4+r][q=l16]
    f32x4 P[4][2];
    __builtin_amdgcn_s_setprio(1);
#pragma unroll
    for (int jh = 0; jh < 4; ++jh)
#pragma unroll
      for (int it2 = 0; it2 < 2; ++it2) {
        f32x4 s = f32x4{0.f, 0.f, 0.f, 0.f};
        s = mfma16(kf[jh][0], qf[it2][0], s);
        s = mfma16(kf[jh][1], qf[it2][1], s);
        P[jh][it2] = s;
      }
    __builtin_amdgcn_s_setprio(0);

    // exp2 + pack to bf16 pairs, all in registers (no scalar lsum adds)
    uint32_t sp[4][2][2];          // [jh][it2][word]: keys {4q+2w, 4q+2w+1}
#pragma unroll
    for (int jh = 0; jh < 4; ++jh)
#pragma unroll
      for (int it2 = 0; it2 < 2; ++it2) {
        float p0 = EXP2F(P[jh][it2][0]);
        float p1 = EXP2F(P[jh][it2][1]);
        float p2 = EXP2F(P[jh][it2][2]);
        float p3 = EXP2F(P[jh][it2][3]);
        sp[jh][it2][0] = cvtpk(p0, p1);
        sp[jh][it2][1] = cvtpk(p2, p3);
      }

    // quad-exchange: B-frag word t_w holds keys {8q+2w,8q+2w+1} of the kp chunk
    bf16x8 pb[2][2];               // [kp][it2]
#pragma unroll
    for (int kp = 0; kp < 2; ++kp)
#pragma unroll
      for (int it2 = 0; it2 < 2; ++it2) {
        uint32_t t0 = sp[2 * kp][it2][0], t2 = sp[2 * kp + 1][it2][0];
        swap32(t0, t2); swap16(t0, t2);
        uint32_t t1 = sp[2 * kp][it2][1], t3 = sp[2 * kp + 1][it2][1];
        swap32(t1, t3); swap16(t1, t3);
        u32x4 w = {t0, t1, t2, t3};
        pb[kp][it2] = __builtin_bit_cast(bf16x8, w);
      }

    // O^T += V^T·P^T per 32-key chunk; lsum += ones·P^T on the same pipe
#pragma unroll
    for (int kp = 0; kp < 2; ++kp) {
      bf16x8 va[4];
#pragma unroll
      for (int dl = 0; dl < 4; ++dl)
        va[dl] = *(const bf16x8*)((const char*)Vs[cur] + (dl * 16 + l16) * 256 +
                                  (((khalf * 8 + kp * 4 + quad) ^ l16) & 15) * 16);
      __builtin_amdgcn_s_setprio(1);
#pragma unroll
      for (int it2 = 0; it2 < 2; ++it2) {
        Lacc[it2] = mfma16(onesf, pb[kp][it2], Lacc[it2]);
#pragma unroll
        for (int dl = 0; dl < 4; ++dl)
          O[it2][dl] = mfma16(va[dl], pb[kp][it2], O[it2][dl]);
      }
      __builtin_amdgcn_s_setprio(0);
    }
  }

  // per-wave lsum: every lane's Lacc[it2][0] = sum over this wave's 64 keys
  float lsum[2] = {Lacc[0][0], Lacc[1][0]};

  // merge partial O / lsum across the wave pair, reusing Ks/Vs LDS
  __syncthreads();
  if (!(wave & 1)) {
    f32x4* ob = (f32x4*)((char*)Ks + pair * 8192);   // 8KB per pair
#pragma unroll
    for (int it2 = 0; it2 < 2; ++it2)
#pragma unroll
      for (int dl = 0; dl < 4; ++dl)
        ob[(it2 * 4 + dl) * 64 + lane] = O[it2][dl];
    float2* lb = (float2*)((char*)Vs + pair * 512);
    lb[lane] = make_float2(lsum[0], lsum[1]);
  }
  __syncthreads();
  if (wave & 1) {
    const f32x4* ob = (const f32x4*)((char*)Ks + pair * 8192);
    float2 lp = ((const float2*)((char*)Vs + pair * 512))[lane];
    lsum[0] += lp.x; lsum[1] += lp.y;
#pragma unroll
    for (int it2 = 0; it2 < 2; ++it2)
#pragma unroll
      for (int dl = 0; dl < 4; ++dl)
        O[it2][dl] += ob[(it2 * 4 + dl) * 64 + lane];

    const int b = bh >> 3, h = bh & 7;
#pragma unroll
    for (int it2 = 0; it2 < 2; ++it2) {
      float inv = 1.0f / lsum[it2];        // lane-complete: no shfl reduce needed
      int q = qt * 128 + pair * 32 + it2 * 16 + l16;
      size_t rowbase = ((size_t)(b * SEQ + q)) * DIMM + h * HDIM;
#pragma unroll
      for (int dl = 0; dl < 4; ++dl) {
        uint2 pk;
        pk.x = cvtpk(O[it2][dl][0] * inv, O[it2][dl][1] * inv);
        pk.y = cvtpk(O[it2][dl][2] * inv, O[it2][dl][3] * inv);
        *(uint2*)(ao + rowbase + dl * 16 + quad * 4) = pk;
      }
    }
  }
}

// ---------------------------------------------------------------------------
// Kernel 4: output projection (M=8192, N=512, K=512) + bias, fp32 out.
// 64x128 tiles -> 512 blocks = 2 blocks/CU. 4 waves side-by-side: wave w
// owns cols [w*32, w*32+32), acc[4][2]. LDS: A 2x4KB + B 2x8KB = 24KB.
// Bijective XCD decode: XCD x owns bm in [16x,16x+16) x all bn.
// ---------------------------------------------------------------------------
__global__ __launch_bounds__(256, 4) void proj_gemm(
    const uint16_t* __restrict__ ao, const uint16_t* __restrict__ wpb,
    const float* __restrict__ bprj, float* __restrict__ out) {
  __shared__ __align__(16) uint16_t As[2][64 * 32];
  __shared__ __align__(16) uint16_t Bs[2][128 * 32];
  const int lin = blockIdx.y * 128 + blockIdx.x;   // 0..511, = HW linear id
  const int idx = lin >> 3;                        // 0..63
  const int bm = (lin & 7) * 16 + (idx >> 2);      // 0..127
  const int bn = idx & 3;                          // 0..3

  const int tid = threadIdx.x;
  const int lane = tid & 63, wave = tid >> 6;
  const int quad = lane >> 4, l16 = lane & 15;
  const int wc = wave * 32;
  const int sw = (l16 >> 1) & 3;

  f32x4 acc[4][2];
#pragma unroll
  for (int i = 0; i < 4; ++i)
#pragma unroll
    for (int j = 0; j < 2; ++j) acc[i][j] = f32x4{0.f, 0.f, 0.f, 0.f};

  auto stage = [&](int buf, int kt) {
    {
      int r = tid >> 2, c = tid & 3;               // A: 64 rows x 4 chunks
      int gc = c ^ ((r >> 1) & 3);
      int ldsoff = (tid & ~63) * 16;
      gld16((const char*)ao + ((size_t)(bm * 64 + r) * DIMM + kt * 32) * 2 + gc * 16,
            (char*)As[buf] + ldsoff);
    }
#pragma unroll
    for (int it = 0; it < 2; ++it) {               // B: 128 rows x 4 chunks
      int L = it * 256 + tid;
      int r = L >> 2, c = L & 3;
      int gc = c ^ ((r >> 1) & 3);
      int ldsoff = (it * 256 + (tid & ~63)) * 16;
      gld16((const char*)wpb + ((size_t)(bn * 128 + r) * DIMM + kt * 32) * 2 + gc * 16,
            (char*)Bs[buf] + ldsoff);
    }
  };

  stage(0, 0);
  for (int kt = 0; kt < DIMM / 32; ++kt) {
    const int cur = kt & 1;
    __syncthreads();
    if (kt < DIMM / 32 - 1) stage(cur ^ 1, kt + 1);

    bf16x8 af[4], bfr[2];
#pragma unroll
    for (int i = 0; i < 4; ++i)
      af[i] = *(const bf16x8*)(As[cur] + (i * 16 + l16) * 32 + ((quad ^ sw) * 8));
#pragma unroll
    for (int j = 0; j < 2; ++j)
      bfr[j] = *(const bf16x8*)(Bs[cur] + (wc + j * 16 + l16) * 32 + ((quad ^ sw) * 8));
    __builtin_amdgcn_s_setprio(1);
#pragma unroll
    for (int i = 0; i < 4; ++i)
#pragma unroll
      for (int j = 0; j < 2; ++j)
        acc[i][j] = mfma16(af[i], bfr[j], acc[i][j]);
    __builtin_amdgcn_s_setprio(0);
  }

#pragma unroll
  for (int i = 0; i < 4; ++i) {
    int m0 = bm * 64 + i * 16 + quad * 4;
#pragma unroll
    for (int j = 0; j < 2; ++j) {
      int jc = bn * 128 + wc + j * 16 + l16;
      float bias = bprj[jc];
#pragma unroll
      for (int r = 0; r < 4; ++r)
        out[(size_t)(m0 + r) * DIMM + jc] = acc[i][j][r] + bias;
    }
  }
}

// ---------------------------------------------------------------------------
extern "C" void kernel_launch(void* const* d_in, const int* in_sizes, int n_in,
                              void* d_out, int out_size, void* d_ws, size_t ws_size,
                              hipStream_t stream) {
  const float* x     = (const float*)d_in[0];
  const float* wqkv  = (const float*)d_in[1];
  const float* wproj = (const float*)d_in[2];
  const float* bproj = (const float*)d_in[3];

  char* ws = (char*)d_ws;
  uint16_t* wqb = (uint16_t*)(ws + 8388608);    //  1,572,864  w_qkv bf16 [1536][512]
  uint16_t* wpb = (uint16_t*)(ws + 9961472);    //    524,288  w_proj bf16 [512][512]
  uint16_t* qd  = (uint16_t*)(ws + 10485760);   //  8,388,608  q bf16 [16][4096][64] (scaled)
  uint16_t* kd  = (uint16_t*)(ws + 18874368);   //  8,388,608  k bf16 [16][4096][64]
  uint16_t* vt  = (uint16_t*)(ws + 27262976);   //  8,388,608  v bf16 [16][64][4096]
  uint16_t* ao  = (uint16_t*)(ws + 35651584);   //  8,388,608  attn out bf16 [8192][512]

  cvt_kernel<<<(Q4 + P4) / 256, 256, 0, stream>>>(wqkv, wproj, wqb, wpb);
  qkv_gemm<<<dim3(64, 12), 256, 0, stream>>>(x, wqb, qd, kd, vt);
  attn_kernel<<<512, 512, 0, stream>>>(qd, kd, vt, ao);
  proj_gemm<<<dim3(128, 4), 256, 0, stream>>>(ao, wpb, bproj, (float*)d_out);
}